// Round 2
// baseline (5245.735 us; speedup 1.0000x reference)
//
#include <hip/hip_runtime.h>
#include <hip/hip_bf16.h>

typedef __hip_bfloat16 bf16_t;

#define N_NODES 10000
#define N_EDGES 100000
#define N_BONDS 1000

__device__ __forceinline__ float bf2f(bf16_t v){ return __bfloat162float(v); }
__device__ __forceinline__ bf16_t f2bf(float v){ return __float2bfloat16(v); }
__device__ __forceinline__ int iabs(int x){ return x<0?-x:x; }

// Store one element to output with runtime-selected width
__device__ __forceinline__ void stout(void* out, size_t idx, float v, bool f32o){
  if (f32o) ((float*)out)[idx]=v;
  else      ((bf16_t*)out)[idx]=f2bf(v);
}

// =====================================================================
// Dtype detection: num_neighbors == 10.0 always. bf16 -> u16[0]==0x4120.
// flag (int at ws[0]) = 1 if inputs are f32, 0 if bf16.
// =====================================================================
__global__ void detect_k(const unsigned short* nnb_raw, int* flag){
  *flag = (nnb_raw[0]==0x4120) ? 0 : 1;
}

struct CvtArgs {
  const void* src[19];
  float* dst[19];
  int n[19];
};

__global__ __launch_bounds__(256) void convert_k(CvtArgs a, const int* flag){
  bool f32 = (*flag)!=0;
  int tid = blockIdx.x*256+threadIdx.x;
  int nth = gridDim.x*256;
  for(int t=0;t<19;++t){
    int n=a.n[t];
    float* d=a.dst[t];
    if (f32){
      const float* s=(const float*)a.src[t];
      for(int i=tid;i<n;i+=nth) d[i]=s[i];
    } else {
      const bf16_t* s=(const bf16_t*)a.src[t];
      for(int i=tid;i<n;i+=nth) d[i]=bf2f(s[i]);
    }
  }
}

// =====================================================================
// CG tables: computed on device in double precision, exact replica of
// the reference _cgc / _c2r / real-vs-imag selection. Dense layout:
// cg[((l1*3+l2)*3+l3)*125 + (i*(2l2+1)+j)*(2l3+1)+k]
// =====================================================================
__device__ __forceinline__ double dfact(int n){
  const double F[11]={1.,1.,2.,6.,24.,120.,720.,5040.,40320.,362880.,3628800.};
  return F[n];
}

__device__ double cgc_d(int j1,int m1,int j2,int m2,int j3,int m3){
  if (m1+m2!=m3) return 0.0;
  double pre = sqrt((double)(2*j3+1)*dfact(j3+j1-j2)*dfact(j3-j1+j2)*dfact(j1+j2-j3)/dfact(j1+j2+j3+1));
  pre *= sqrt(dfact(j3+m3)*dfact(j3-m3)*dfact(j1-m1)*dfact(j1+m1)*dfact(j2-m2)*dfact(j2+m2));
  int k0 = max(0, max(j2-j3-m1, j1-j3+m2));
  int k1 = min(j1+j2-j3, min(j1-m1, j2+m2));
  double s=0.0;
  for(int k=k0;k<=k1;++k)
    s += ((k&1)?-1.0:1.0)/(dfact(k)*dfact(j1+j2-j3-k)*dfact(j1-m1-k)*dfact(j2+m2-k)*dfact(j3-j2+m1+k)*dfact(j3-j1-m2+k));
  return pre*s;
}

__device__ void c2r_d(int l,int a,int m,double&re,double&im){
  re=0.0; im=0.0;
  const double r2 = 0.7071067811865475244;
  int mu = a-l;
  if (mu==0){ if (m==l) re=1.0; return; }
  if (mu>0){
    if (m==l+mu) re = (mu&1)? -r2 : r2;
    else if (m==l-mu) re = r2;
  } else {
    int nu=-mu;
    if (m==l-nu) im = r2;
    else if (m==l+nu) im = (nu&1)? r2 : -r2;
  }
}

__global__ __launch_bounds__(128) void cg_init_k(float* cg){
  int b=blockIdx.x;
  int l1=b/9, l2=(b/3)%3, l3=b%3;
  if (l3 < iabs(l1-l2) || l3 > l1+l2) return;
  int n1=2*l1+1,n2=2*l2+1,n3=2*l3+1,n=n1*n2*n3;
  __shared__ double sRe[125], sIm[125];
  __shared__ int sPick;
  int t=threadIdx.x;
  if (t<n){
    int a=t/(n2*n3), bb=(t/n3)%n2, c=t%n3;
    double re=0.0, im=0.0;
    for(int m1=0;m1<n1;++m1){
      double q1r,q1i; c2r_d(l1,a,m1,q1r,q1i);
      if (q1r==0.0 && q1i==0.0) continue;
      for(int m2=0;m2<n2;++m2){
        double q2r,q2i; c2r_d(l2,bb,m2,q2r,q2i);
        if (q2r==0.0 && q2i==0.0) continue;
        int m3=(m1-l1)+(m2-l2)+l3;
        if (m3<0||m3>=n3) continue;
        double q3r,q3i; c2r_d(l3,c,m3,q3r,q3i); q3i=-q3i;
        double C = cgc_d(l1,m1-l1,l2,m2-l2,l3,m3-l3);
        if (C==0.0) continue;
        double ar = q1r*q2r - q1i*q2i;
        double ai = q1r*q2i + q1i*q2r;
        re += (ar*q3r - ai*q3i)*C;
        im += (ar*q3i + ai*q3r)*C;
      }
    }
    sRe[t]=re; sIm[t]=im;
  }
  __syncthreads();
  if (t==0){
    double s1=0.0,s2=0.0;
    for(int i=0;i<n;++i){ s1+=fabs(sRe[i]); s2+=fabs(sIm[i]); }
    sPick = (s1>=s2)?1:0;
  }
  __syncthreads();
  if (t<n) cg[b*125+t] = (float)(sPick? sRe[t] : sIm[t]);
}

// =====================================================================
// Stage A: x1 = tanh(f_in @ W(2x2) / sqrt(2))
// =====================================================================
__global__ __launch_bounds__(256) void nodeA_k(const float* __restrict__ fin,
                                               const float* __restrict__ w,
                                               float* __restrict__ x1){
  int n=blockIdx.x*256+threadIdx.x; if(n>=N_NODES) return;
  float f0=fin[2*n], f1=fin[2*n+1];
  const float r2=0.70710678f;
  x1[2*n]   = tanhf((f0*w[0]+f1*w[2])*r2);
  x1[2*n+1] = tanhf((f0*w[1]+f1*w[3])*r2);
}

// MLP [1,16,16,16] with relu after each layer (fc_apply layers 0..2)
__device__ __forceinline__ void mlp16(float e, const float* __restrict__ w, float* h){
  float a[16];
  #pragma unroll
  for(int j=0;j<16;++j) a[j]=fmaxf(e*w[j],0.f);
  float b[16];
  #pragma unroll
  for(int j=0;j<16;++j){
    float s=0.f;
    #pragma unroll
    for(int i=0;i<16;++i) s+=a[i]*w[16+i*16+j];
    b[j]=fmaxf(s*0.25f,0.f);
  }
  #pragma unroll
  for(int j=0;j<16;++j){
    float s=0.f;
    #pragma unroll
    for(int i=0;i<16;++i) s+=b[i]*w[272+i*16+j];
    h[j]=fmaxf(s*0.25f,0.f);
  }
}

// =====================================================================
// Edge conv 1: TP(2x0e x SH -> MID1) with per-edge FC weights, scatter.
// =====================================================================
template<int D,int BO,int OO,int P>
__device__ __forceinline__ void tp1_path(const float* __restrict__ b, const float* __restrict__ h,
    const float* __restrict__ wfc, float a0, float a1, float scale, float* __restrict__ outp){
  #pragma unroll
  for(int w8=0;w8<8;++w8){
    float w0=0.f,w1=0.f;
    #pragma unroll
    for(int i=0;i<16;++i){
      float hv=h[i];
      w0+=hv*wfc[528+i*48+P*16+w8];
      w1+=hv*wfc[528+i*48+P*16+8+w8];
    }
    float s=(w0*a0+w1*a1)*0.25f*scale;
    #pragma unroll
    for(int j=0;j<D;++j) atomicAdd(&outp[OO+w8*D+j], s*b[BO+j]);
  }
}

__global__ __launch_bounds__(256) void edge1_k(const float* __restrict__ x1,
    const float* __restrict__ sh, const float* __restrict__ emb,
    const float* __restrict__ wfc, const int* __restrict__ esrc,
    const int* __restrict__ edst, const float* __restrict__ nnb,
    float* __restrict__ xout){
  int e=blockIdx.x*256+threadIdx.x; if(e>=N_EDGES) return;
  float inv = rsqrtf(nnb[0]);
  const float c = 0.70710678f*inv;
  float h[16]; mlp16(emb[e], wfc, h);
  int src=esrc[e], dst=edst[e];
  float a0=x1[2*src], a1=x1[2*src+1];
  float b[9];
  #pragma unroll
  for(int j=0;j<9;++j) b[j]=sh[(size_t)e*9+j];
  float* outp = xout + (size_t)dst*72;
  tp1_path<1,0,0,0>(b,h,wfc,a0,a1,c,outp);
  tp1_path<3,1,8,1>(b,h,wfc,a0,a1,c,outp);
  tp1_path<5,4,32,2>(b,h,wfc,a0,a1,c,outp);
}

// =====================================================================
// Block-diagonal linear (8ch per irrep slice), /sqrt(8), optional tanh
// =====================================================================
template<int L>
__device__ __forceinline__ void diag_block(float* Xs, const float* __restrict__ w, bool dotanh){
  constexpr int D=2*L+1;
  const float r8=0.35355339f;
  float in[8*D];
  #pragma unroll
  for(int t=0;t<8*D;++t) in[t]=Xs[t];
  #pragma unroll
  for(int v=0;v<8;++v){
    #pragma unroll
    for(int i=0;i<D;++i){
      float acc=0.f;
      #pragma unroll
      for(int u=0;u<8;++u) acc+=in[u*D+i]*w[u*8+v];
      acc*=r8;
      Xs[v*D+i]= dotanh? tanhf(acc):acc;
    }
  }
}

__global__ __launch_bounds__(256) void lin2_k(float* __restrict__ x, const float* __restrict__ w){
  int n=blockIdx.x*256+threadIdx.x; if(n>=N_NODES) return;
  float* X=x+(size_t)n*72;
  diag_block<0>(X,    w,     true);
  diag_block<1>(X+8,  w+64,  false);
  diag_block<2>(X+32, w+128, false);
}

__global__ __launch_bounds__(256) void lin3_k(float* __restrict__ x, const float* __restrict__ w){
  int n=blockIdx.x*256+threadIdx.x; if(n>=N_NODES) return;
  float* X=x+(size_t)n*144;
  diag_block<0>(X,     w,     true);
  diag_block<0>(X+8,   w+64,  true);
  diag_block<1>(X+16,  w+128, false);
  diag_block<1>(X+40,  w+192, false);
  diag_block<2>(X+64,  w+256, false);
  diag_block<2>(X+104, w+320, false);
}

// =====================================================================
// Edge conv 2: TP(MID1 x SH -> MID2), per-edge FC weights (fused)
// =====================================================================
template<int L1,int L2,int LO,int AO,int BO,int WB>
__device__ __forceinline__ void tp2_path(const float* __restrict__ A, const float* __restrict__ b,
    const float* __restrict__ cg, const float* __restrict__ h,
    const float* __restrict__ w3, float* __restrict__ ch){
  constexpr int D1=2*L1+1, D2=2*L2+1, DN=2*LO+1;
  const float* C = cg + ((L1*3+L2)*3+LO)*125;
  float av[8][D1];
  #pragma unroll
  for(int u=0;u<8;++u){
    #pragma unroll
    for(int i=0;i<D1;++i) av[u][i]=A[AO+u*D1+i];
  }
  float t[8][DN];
  #pragma unroll
  for(int u=0;u<8;++u){
    #pragma unroll
    for(int k=0;k<DN;++k) t[u][k]=0.f;
  }
  #pragma unroll
  for(int i=0;i<D1;++i){
    #pragma unroll
    for(int j=0;j<D2;++j){
      #pragma unroll
      for(int k=0;k<DN;++k){
        float cv=C[(i*D2+j)*DN+k];
        if (cv!=0.f){
          float cb=cv*b[BO+j];
          #pragma unroll
          for(int u=0;u<8;++u) t[u][k]+=av[u][i]*cb;
        }
      }
    }
  }
  #pragma unroll
  for(int w=0;w<8;++w){
    #pragma unroll
    for(int u=0;u<8;++u){
      float ww=0.f;
      #pragma unroll
      for(int i=0;i<16;++i) ww+=h[i]*w3[528+i*960+WB+u*8+w];
      ww*=0.25f;
      #pragma unroll
      for(int k=0;k<DN;++k) ch[w*DN+k]+=ww*t[u][k];
    }
  }
}

__global__ __launch_bounds__(256) void edge2_k(const float* __restrict__ xn,
    const float* __restrict__ sh, const float* __restrict__ emb,
    const float* __restrict__ wfc, const int* __restrict__ esrc,
    const int* __restrict__ edst, const float* __restrict__ nnb,
    const float* __restrict__ cg, float* __restrict__ xout){
  int e=blockIdx.x*256+threadIdx.x; if(e>=N_EDGES) return;
  float inv = rsqrtf(nnb[0]);
  int src=esrc[e], dst=edst[e];
  const float* A = xn + (size_t)src*72;
  float b[9];
  #pragma unroll
  for(int j=0;j<9;++j) b[j]=sh[(size_t)e*9+j];
  float h[16]; mlp16(emb[e], wfc, h);
  float* out = xout + (size_t)dst*144;
  { // 0e (off 0), fan 24
    float ch[8]={0};
    tp2_path<0,0,0,0,0,0>(A,b,cg,h,wfc,ch);
    tp2_path<1,1,0,8,1,256>(A,b,cg,h,wfc,ch);
    tp2_path<2,2,0,32,4,768>(A,b,cg,h,wfc,ch);
    float f=rsqrtf(24.f)*inv;
    #pragma unroll
    for(int t=0;t<8;++t) atomicAdd(&out[0+t], ch[t]*f);
  }
  { // 1e (off 16), fan 16
    float ch[24]={0};
    tp2_path<1,1,1,8,1,320>(A,b,cg,h,wfc,ch);
    tp2_path<2,2,1,32,4,832>(A,b,cg,h,wfc,ch);
    float f=rsqrtf(16.f)*inv;
    #pragma unroll
    for(int t=0;t<24;++t) atomicAdd(&out[16+t], ch[t]*f);
  }
  { // 1o (off 40), fan 32
    float ch[24]={0};
    tp2_path<0,1,1,0,1,64>(A,b,cg,h,wfc,ch);
    tp2_path<1,0,1,8,0,192>(A,b,cg,h,wfc,ch);
    tp2_path<1,2,1,8,4,448>(A,b,cg,h,wfc,ch);
    tp2_path<2,1,1,32,1,640>(A,b,cg,h,wfc,ch);
    float f=rsqrtf(32.f)*inv;
    #pragma unroll
    for(int t=0;t<24;++t) atomicAdd(&out[40+t], ch[t]*f);
  }
  { // 2e (off 64), fan 32
    float ch[40]={0};
    tp2_path<0,2,2,0,4,128>(A,b,cg,h,wfc,ch);
    tp2_path<1,1,2,8,1,384>(A,b,cg,h,wfc,ch);
    tp2_path<2,0,2,32,0,576>(A,b,cg,h,wfc,ch);
    tp2_path<2,2,2,32,4,896>(A,b,cg,h,wfc,ch);
    float f=rsqrtf(32.f)*inv;
    #pragma unroll
    for(int t=0;t<40;++t) atomicAdd(&out[64+t], ch[t]*f);
  }
  { // 2o (off 104), fan 16
    float ch[40]={0};
    tp2_path<1,2,2,8,4,512>(A,b,cg,h,wfc,ch);
    tp2_path<2,1,2,32,1,704>(A,b,cg,h,wfc,ch);
    float f=rsqrtf(16.f)*inv;
    #pragma unroll
    for(int t=0;t<40;++t) atomicAdd(&out[104+t], ch[t]*f);
  }
}

// =====================================================================
// Generic irrep linear from MID2-layout input, fan=8 per output slice.
// Zero-fills the whole output row first (covers l=3/l=4 slices).
// =====================================================================
struct IrS{ short off,m,l,p; };
__device__ const IrS SL_MID2[6]={{0,8,0,1},{8,8,0,-1},{16,8,1,1},{40,8,1,-1},{64,8,2,1},{104,8,2,-1}};
__device__ const IrS SL_HH[6]={{0,4,0,1},{4,2,1,-1},{10,2,1,-1},{16,1,0,1},{17,1,1,1},{20,1,2,1}};
__device__ const IrS SL_CC[34]={{0,9,0,1},{9,6,1,-1},{27,3,2,1},{42,6,1,-1},
 {60,1,0,1},{61,1,1,1},{64,1,2,1},{69,1,0,1},{70,1,1,1},{73,1,2,1},
 {78,1,0,1},{79,1,1,1},{82,1,2,1},{87,1,0,1},{88,1,1,1},{91,1,2,1},
 {96,1,1,-1},{99,1,2,-1},{104,1,3,-1},{111,1,1,-1},{114,1,2,-1},{119,1,3,-1},
 {126,3,2,1},{141,1,1,-1},{144,1,2,-1},{149,1,3,-1},{156,1,1,-1},{159,1,2,-1},{164,1,3,-1},
 {171,1,0,1},{172,1,1,1},{175,1,2,1},{180,1,3,1},{187,1,4,1}};
__device__ const IrS SL_CH[13]={{0,6,0,1},{6,3,1,-1},{15,4,1,-1},{27,1,0,1},{28,1,1,1},{31,1,2,1},
 {36,1,0,1},{37,1,1,1},{40,1,2,1},{45,2,2,1},{55,1,1,-1},{58,1,2,-1},{63,1,3,-1}};

__device__ void lin_out(const float* __restrict__ x, bool act16, const float* __restrict__ w,
                        const IrS* so, int no, int dim,
                        void* out, size_t base, bool f32o, float scale){
  float tx[16];
  if (act16){
    #pragma unroll
    for(int i=0;i<16;++i) tx[i]=tanhf(x[i]);
  }
  for(int i=0;i<dim;++i) stout(out, base+i, 0.f, f32o);
  int woff=0;
  for(int a=0;a<6;++a){
    int la=SL_MID2[a].l, pa=SL_MID2[a].p, oa=SL_MID2[a].off;
    int d=2*la+1;
    for(int bI=0;bI<no;++bI){
      if (so[bI].l!=la || so[bI].p!=pa) continue;
      int mo=so[bI].m;
      float f = 0.35355339f*scale;
      for(int v=0;v<mo;++v){
        for(int i=0;i<d;++i){
          float acc=0.f;
          for(int u=0;u<8;++u){
            int idx=oa+u*d+i;
            float xv=(act16 && idx<16)? tx[idx] : x[idx];
            acc+=xv*w[woff+u*mo+v];
          }
          stout(out, base+so[bI].off+v*d+i, acc*f, f32o);
        }
      }
      woff+=8*mo;
    }
  }
}

// =====================================================================
// Node outputs: nH (out0, *0.2), nC (out1, *0.2), screen (out5)
// =====================================================================
__global__ __launch_bounds__(256) void node_out_k(const float* __restrict__ x,
    const float* __restrict__ wC, const float* __restrict__ wH,
    const float* __restrict__ ws1, const float* __restrict__ ws2,
    void* out, const int* __restrict__ flag){
  int n=blockIdx.x*256+threadIdx.x; if(n>=N_NODES) return;
  bool f32o = (*flag)!=0;
  const float* X = x + (size_t)n*144;
  lin_out(X,false,wH,SL_HH,6,25,   out, (size_t)n*25, f32o, 0.2f);
  lin_out(X,false,wC,SL_CC,34,196, out, 250000 + (size_t)n*196, f32o, 0.2f);
  const float r8=0.35355339f, r32=0.17677670f;
  float t0[32];
  for(int v=0;v<32;++v){
    float acc=0.f;
    #pragma unroll
    for(int u=0;u<8;++u) acc+=X[u]*ws1[u*32+v];
    t0[v]=tanhf(acc*r8);
  }
  float t2[5];
  #pragma unroll
  for(int i=0;i<5;++i){
    float acc=0.f;
    #pragma unroll
    for(int u=0;u<8;++u) acc+=X[64+u*5+i]*ws1[256+u];
    t2[i]=acc*r8;
  }
  size_t sb = 2501000 + (size_t)n*6;
  float acc=0.f;
  for(int v=0;v<32;++v) acc+=t0[v]*ws2[v];
  stout(out, sb, acc*r32, f32o);
  float w2e=ws2[32];
  #pragma unroll
  for(int i=0;i<5;++i) stout(out, sb+1+i, t2[i]*w2e, f32o);
}

// =====================================================================
// Bond TP: one wave per bond. TP(MID2 x MID2 -> MID2), 60 paths.
// =====================================================================
template<int L1,int L2,int LO>
__device__ __forceinline__ void bond_path(const float* sa,int ao,const float* sb,int bo,
    const float* __restrict__ cg, const float* __restrict__ h3,
    const float* __restrict__ wb, int wbase, float invfan,
    float* sP, float* sF, int oo, int lane){
  constexpr int D1=2*L1+1, D2=2*L2+1, DN=2*LO+1;
  const float* C = cg + ((L1*3+L2)*3+LO)*125;
  int u=lane>>3, v=lane&7;
  float P[DN];
  #pragma unroll
  for(int k=0;k<DN;++k) P[k]=0.f;
  #pragma unroll
  for(int i=0;i<D1;++i){
    float avv=sa[ao+u*D1+i];
    #pragma unroll
    for(int j=0;j<D2;++j){
      float ab=avv*sb[bo+v*D2+j];
      #pragma unroll
      for(int k=0;k<DN;++k){
        float cv=C[(i*D2+j)*DN+k];
        if(cv!=0.f) P[k]+=ab*cv;
      }
    }
  }
  #pragma unroll
  for(int k=0;k<DN;++k) sP[lane*5+k]=P[k];
  __syncthreads();
  int v2=lane>>3, w=lane&7;
  float acc[DN];
  #pragma unroll
  for(int k=0;k<DN;++k) acc[k]=0.f;
  #pragma unroll
  for(int u2=0;u2<8;++u2){
    float ww=0.f;
    int col=wbase + u2*64 + v2*8 + w;
    #pragma unroll
    for(int i=0;i<16;++i) ww+=h3[i]*wb[528+i*30720+col];
    ww*=0.25f;
    #pragma unroll
    for(int k=0;k<DN;++k) acc[k]+=ww*sP[(u2*8+v2)*5+k];
  }
  #pragma unroll
  for(int k=0;k<DN;++k){
    acc[k]+=__shfl_xor(acc[k],8,64);
    acc[k]+=__shfl_xor(acc[k],16,64);
    acc[k]+=__shfl_xor(acc[k],32,64);
  }
  if (v2==0){
    #pragma unroll
    for(int k=0;k<DN;++k) sF[oo+w*DN+k]+=acc[k]*invfan;
  }
  __syncthreads();
}

__global__ __launch_bounds__(256) void bond_tp_k(const float* __restrict__ xn,
    const float* __restrict__ emb, const float* __restrict__ wb,
    const int* __restrict__ esrc, const int* __restrict__ edst,
    const int* __restrict__ ind, const float* __restrict__ cg,
    float* __restrict__ Fout){
  __shared__ float sA[4][144], sB[4][144], sF[4][144], sP[4][320];
  int wid=threadIdx.x>>6, lane=threadIdx.x&63;
  int e=blockIdx.x*4+wid;
  int ie=ind[e];
  int src=esrc[ie], dst=edst[ie];
  for(int t=lane;t<144;t+=64){
    sA[wid][t]=xn[(size_t)src*144+t];
    sB[wid][t]=xn[(size_t)dst*144+t];
    sF[wid][t]=0.f;
  }
  float h3[16]; mlp16(emb[ie], wb, h3);
  __syncthreads();
  const int SL_L[6]={0,0,1,1,2,2};
  const int SL_P[6]={1,-1,1,-1,1,-1};
  const int SL_O[6]={0,8,16,40,64,104};
  const float fi0=rsqrtf(384.f), fi1=rsqrtf(768.f);
  int wbase=0;
  for(int s1=0;s1<6;++s1){
    for(int s2=0;s2<6;++s2){
      for(int so=0;so<6;++so){
        int l1=SL_L[s1], l2=SL_L[s2], lo=SL_L[so];
        if (SL_P[so]!=SL_P[s1]*SL_P[s2]) continue;
        if (lo<iabs(l1-l2) || lo>l1+l2) continue;
        int code=l1*9+l2*3+lo;
        float* a=sA[wid]; float* bb=sB[wid]; float* P=sP[wid]; float* F=sF[wid];
        int ao=SL_O[s1], bo=SL_O[s2], oo=SL_O[so];
        float fv = (lo==0)? fi0 : fi1;
        switch(code){
          case 0:  bond_path<0,0,0>(a,ao,bb,bo,cg,h3,wb,wbase,fv,P,F,oo,lane); break;
          case 4:  bond_path<0,1,1>(a,ao,bb,bo,cg,h3,wb,wbase,fv,P,F,oo,lane); break;
          case 8:  bond_path<0,2,2>(a,ao,bb,bo,cg,h3,wb,wbase,fv,P,F,oo,lane); break;
          case 10: bond_path<1,0,1>(a,ao,bb,bo,cg,h3,wb,wbase,fv,P,F,oo,lane); break;
          case 12: bond_path<1,1,0>(a,ao,bb,bo,cg,h3,wb,wbase,fv,P,F,oo,lane); break;
          case 13: bond_path<1,1,1>(a,ao,bb,bo,cg,h3,wb,wbase,fv,P,F,oo,lane); break;
          case 14: bond_path<1,1,2>(a,ao,bb,bo,cg,h3,wb,wbase,fv,P,F,oo,lane); break;
          case 16: bond_path<1,2,1>(a,ao,bb,bo,cg,h3,wb,wbase,fv,P,F,oo,lane); break;
          case 17: bond_path<1,2,2>(a,ao,bb,bo,cg,h3,wb,wbase,fv,P,F,oo,lane); break;
          case 20: bond_path<2,0,2>(a,ao,bb,bo,cg,h3,wb,wbase,fv,P,F,oo,lane); break;
          case 22: bond_path<2,1,1>(a,ao,bb,bo,cg,h3,wb,wbase,fv,P,F,oo,lane); break;
          case 23: bond_path<2,1,2>(a,ao,bb,bo,cg,h3,wb,wbase,fv,P,F,oo,lane); break;
          case 24: bond_path<2,2,0>(a,ao,bb,bo,cg,h3,wb,wbase,fv,P,F,oo,lane); break;
          case 25: bond_path<2,2,1>(a,ao,bb,bo,cg,h3,wb,wbase,fv,P,F,oo,lane); break;
          case 26: bond_path<2,2,2>(a,ao,bb,bo,cg,h3,wb,wbase,fv,P,F,oo,lane); break;
        }
        wbase+=512;
      }
    }
  }
  __syncthreads();
  for(int t=lane;t<144;t+=64) Fout[(size_t)e*144+t]=sF[wid][t];
}

// =====================================================================
// Bond outputs: eXX = lin(act(F)) * 0.2 ; gap = L_G2(tanh(L_G1(F_raw)))
// =====================================================================
__global__ __launch_bounds__(256) void bond_out_k(const float* __restrict__ F,
    const float* __restrict__ wlin, int tbl, void* out, size_t baseE,
    const float* __restrict__ wg1, const float* __restrict__ wg2,
    size_t baseG, const int* __restrict__ flag){
  int n=blockIdx.x*256+threadIdx.x; if(n>=N_BONDS) return;
  bool f32o = (*flag)!=0;
  const float* X=F+(size_t)n*144;
  const IrS* so; int no; int dim;
  if(tbl==0){so=SL_HH;no=6;dim=25;}
  else if(tbl==1){so=SL_CC;no=34;dim=196;}
  else {so=SL_CH;no=13;dim=70;}
  lin_out(X,true,wlin,so,no,dim,out,baseE+(size_t)n*dim,f32o,0.2f);
  const float r8=0.35355339f, r32=0.17677670f;
  float g[32];
  for(int v=0;v<32;++v){
    float acc=0.f;
    #pragma unroll
    for(int u=0;u<8;++u) acc+=X[u]*wg1[u*32+v];
    g[v]=tanhf(acc*r8);
  }
  #pragma unroll
  for(int c=0;c<3;++c){
    float acc=0.f;
    for(int v=0;v<32;++v) acc+=g[v]*wg2[v*3+c];
    stout(out, baseG+(size_t)n*3+c, acc*r32, f32o);
  }
}

// =====================================================================
extern "C" void kernel_launch(void* const* d_in, const int* in_sizes, int n_in,
                              void* d_out, int out_size, void* d_ws, size_t ws_size,
                              hipStream_t stream){
  const int* esrc=(const int*)d_in[19];
  const int* edst=(const int*)d_in[20];
  const int* iHH =(const int*)d_in[21];
  const int* iCC =(const int*)d_in[22];
  const int* iCH =(const int*)d_in[23];
  float* ws=(float*)d_ws;
  int* flag=(int*)d_ws;

  // workspace layout (floats)
  size_t off=16;
  auto alloc=[&](size_t n){ size_t o=off; off+=(n+15)&~(size_t)15; return o; };
  size_t o_cg = alloc(27*125);
  // staged f32 inputs (19 float tensors: indices 0..18)
  size_t o_st[19];
  for(int i=0;i<19;++i) o_st[i]=alloc((size_t)in_sizes[i]);
  size_t o_x1  = alloc(20000);
  size_t o_xM1 = alloc(720000);
  size_t o_xM2 = alloc(1440000);
  size_t o_F0  = alloc(144000);
  size_t o_F1  = alloc(144000);
  size_t o_F2  = alloc(144000);

  float* cg  = ws+o_cg;
  float* x1  = ws+o_x1;
  float* xM1 = ws+o_xM1;
  float* xM2 = ws+o_xM2;
  float* F0  = ws+o_F0;
  float* F1  = ws+o_F1;
  float* F2  = ws+o_F2;

  CvtArgs ca;
  for(int i=0;i<19;++i){ ca.src[i]=d_in[i]; ca.dst[i]=ws+o_st[i]; ca.n[i]=in_sizes[i]; }
  const float* f_in   = ws+o_st[0];
  const float* sh     = ws+o_st[1];
  const float* emb    = ws+o_st[2];
  const float* nnb    = ws+o_st[3];
  const float* w_lin1 = ws+o_st[4];
  const float* w_lin2 = ws+o_st[5];
  const float* w_lin3 = ws+o_st[6];
  const float* w_linCC= ws+o_st[7];
  const float* w_linHH= ws+o_st[8];
  const float* w_linCH= ws+o_st[9];
  const float* w_linC = ws+o_st[10];
  const float* w_linH = ws+o_st[11];
  const float* w_s1   = ws+o_st[12];
  const float* w_s2   = ws+o_st[13];
  const float* w_g1   = ws+o_st[14];
  const float* w_g2   = ws+o_st[15];
  const float* w_fc1  = ws+o_st[16];
  const float* w_fc2  = ws+o_st[17];
  const float* w_fcb  = ws+o_st[18];

  detect_k<<<1,1,0,stream>>>((const unsigned short*)d_in[3], flag);
  convert_k<<<512,256,0,stream>>>(ca, flag);
  hipMemsetAsync(xM1, 0, 720000*sizeof(float), stream);
  hipMemsetAsync(xM2, 0, 1440000*sizeof(float), stream);

  cg_init_k<<<27,128,0,stream>>>(cg);
  nodeA_k<<<40,256,0,stream>>>(f_in,w_lin1,x1);
  edge1_k<<<391,256,0,stream>>>(x1,sh,emb,w_fc1,esrc,edst,nnb,xM1);
  lin2_k<<<40,256,0,stream>>>(xM1,w_lin2);
  edge2_k<<<391,256,0,stream>>>(xM1,sh,emb,w_fc2,esrc,edst,nnb,cg,xM2);
  lin3_k<<<40,256,0,stream>>>(xM2,w_lin3);
  node_out_k<<<40,256,0,stream>>>(xM2,w_linC,w_linH,w_s1,w_s2,d_out,flag);
  bond_tp_k<<<250,256,0,stream>>>(xM2,emb,w_fcb,esrc,edst,iHH,cg,F0);
  bond_tp_k<<<250,256,0,stream>>>(xM2,emb,w_fcb,esrc,edst,iCC,cg,F1);
  bond_tp_k<<<250,256,0,stream>>>(xM2,emb,w_fcb,esrc,edst,iCH,cg,F2);
  // out layout: 0:nH@0 1:nC@250000 2:eHH@2210000 3:eCH@2235000 4:eCC@2305000
  //             5:screen@2501000 6:gapCC@2561000 7:gapHH@2564000 8:gapCH@2567000
  bond_out_k<<<4,256,0,stream>>>(F0,w_linHH,0,d_out,2210000,w_g1,w_g2,2564000,flag);
  bond_out_k<<<4,256,0,stream>>>(F1,w_linCC,1,d_out,2305000,w_g1,w_g2,2561000,flag);
  bond_out_k<<<4,256,0,stream>>>(F2,w_linCH,2,d_out,2235000,w_g1,w_g2,2567000,flag);
}

// Round 3
// 3214.370 us; speedup vs baseline: 1.6320x; 1.6320x over previous
//
#include <hip/hip_runtime.h>
#include <hip/hip_bf16.h>

typedef __hip_bfloat16 bf16_t;

#define N_NODES 10000
#define N_EDGES 100000
#define N_BONDS 1000

__device__ __forceinline__ float bf2f(bf16_t v){ return __bfloat162float(v); }
__device__ __forceinline__ bf16_t f2bf(float v){ return __float2bfloat16(v); }
__device__ __forceinline__ int iabs(int x){ return x<0?-x:x; }

__device__ __forceinline__ void stout(void* out, size_t idx, float v, bool f32o){
  if (f32o) ((float*)out)[idx]=v;
  else      ((bf16_t*)out)[idx]=f2bf(v);
}

// =====================================================================
// Dtype detection: num_neighbors == 10.0 always. bf16 -> u16[0]==0x4120.
// =====================================================================
__global__ void detect_k(const unsigned short* nnb_raw, int* flag){
  *flag = (nnb_raw[0]==0x4120) ? 0 : 1;
}

struct CvtArgs {
  const void* src[19];
  float* dst[19];
  int n[19];
};

__global__ __launch_bounds__(256) void convert_k(CvtArgs a, const int* flag){
  bool f32 = (*flag)!=0;
  int tid = blockIdx.x*256+threadIdx.x;
  int nth = gridDim.x*256;
  for(int t=0;t<19;++t){
    int n=a.n[t];
    float* d=a.dst[t];
    if (f32){
      const float* s=(const float*)a.src[t];
      for(int i=tid;i<n;i+=nth) d[i]=s[i];
    } else {
      const bf16_t* s=(const bf16_t*)a.src[t];
      for(int i=tid;i<n;i+=nth) d[i]=bf2f(s[i]);
    }
  }
}

// =====================================================================
// CG tables (device, double precision, exact replica of reference)
// =====================================================================
__device__ __forceinline__ double dfact(int n){
  const double F[11]={1.,1.,2.,6.,24.,120.,720.,5040.,40320.,362880.,3628800.};
  return F[n];
}

__device__ double cgc_d(int j1,int m1,int j2,int m2,int j3,int m3){
  if (m1+m2!=m3) return 0.0;
  double pre = sqrt((double)(2*j3+1)*dfact(j3+j1-j2)*dfact(j3-j1+j2)*dfact(j1+j2-j3)/dfact(j1+j2+j3+1));
  pre *= sqrt(dfact(j3+m3)*dfact(j3-m3)*dfact(j1-m1)*dfact(j1+m1)*dfact(j2-m2)*dfact(j2+m2));
  int k0 = max(0, max(j2-j3-m1, j1-j3+m2));
  int k1 = min(j1+j2-j3, min(j1-m1, j2+m2));
  double s=0.0;
  for(int k=k0;k<=k1;++k)
    s += ((k&1)?-1.0:1.0)/(dfact(k)*dfact(j1+j2-j3-k)*dfact(j1-m1-k)*dfact(j2+m2-k)*dfact(j3-j2+m1+k)*dfact(j3-j1-m2+k));
  return pre*s;
}

__device__ void c2r_d(int l,int a,int m,double&re,double&im){
  re=0.0; im=0.0;
  const double r2 = 0.7071067811865475244;
  int mu = a-l;
  if (mu==0){ if (m==l) re=1.0; return; }
  if (mu>0){
    if (m==l+mu) re = (mu&1)? -r2 : r2;
    else if (m==l-mu) re = r2;
  } else {
    int nu=-mu;
    if (m==l-nu) im = r2;
    else if (m==l+nu) im = (nu&1)? r2 : -r2;
  }
}

__global__ __launch_bounds__(128) void cg_init_k(float* cg){
  int b=blockIdx.x;
  int l1=b/9, l2=(b/3)%3, l3=b%3;
  if (l3 < iabs(l1-l2) || l3 > l1+l2) return;
  int n1=2*l1+1,n2=2*l2+1,n3=2*l3+1,n=n1*n2*n3;
  __shared__ double sRe[125], sIm[125];
  __shared__ int sPick;
  int t=threadIdx.x;
  if (t<n){
    int a=t/(n2*n3), bb=(t/n3)%n2, c=t%n3;
    double re=0.0, im=0.0;
    for(int m1=0;m1<n1;++m1){
      double q1r,q1i; c2r_d(l1,a,m1,q1r,q1i);
      if (q1r==0.0 && q1i==0.0) continue;
      for(int m2=0;m2<n2;++m2){
        double q2r,q2i; c2r_d(l2,bb,m2,q2r,q2i);
        if (q2r==0.0 && q2i==0.0) continue;
        int m3=(m1-l1)+(m2-l2)+l3;
        if (m3<0||m3>=n3) continue;
        double q3r,q3i; c2r_d(l3,c,m3,q3r,q3i); q3i=-q3i;
        double C = cgc_d(l1,m1-l1,l2,m2-l2,l3,m3-l3);
        if (C==0.0) continue;
        double ar = q1r*q2r - q1i*q2i;
        double ai = q1r*q2i + q1i*q2r;
        re += (ar*q3r - ai*q3i)*C;
        im += (ar*q3i + ai*q3r)*C;
      }
    }
    sRe[t]=re; sIm[t]=im;
  }
  __syncthreads();
  if (t==0){
    double s1=0.0,s2=0.0;
    for(int i=0;i<n;++i){ s1+=fabs(sRe[i]); s2+=fabs(sIm[i]); }
    sPick = (s1>=s2)?1:0;
  }
  __syncthreads();
  if (t<n) cg[b*125+t] = (float)(sPick? sRe[t] : sIm[t]);
}

// =====================================================================
// Stage A: x1 = tanh(f_in @ W(2x2) / sqrt(2))
// =====================================================================
__global__ __launch_bounds__(256) void nodeA_k(const float* __restrict__ fin,
                                               const float* __restrict__ w,
                                               float* __restrict__ x1){
  int n=blockIdx.x*256+threadIdx.x; if(n>=N_NODES) return;
  float f0=fin[2*n], f1=fin[2*n+1];
  const float r2=0.70710678f;
  x1[2*n]   = tanhf((f0*w[0]+f1*w[2])*r2);
  x1[2*n+1] = tanhf((f0*w[1]+f1*w[3])*r2);
}

// MLP [1,16,16,16] layers 0..2 of fc_apply (relu after each)
__device__ __forceinline__ void mlp16(float e, const float* w, float* h){
  float a[16];
  #pragma unroll
  for(int j=0;j<16;++j) a[j]=fmaxf(e*w[j],0.f);
  float b[16];
  #pragma unroll
  for(int j=0;j<16;++j){
    float s=0.f;
    #pragma unroll
    for(int i=0;i<16;++i) s+=a[i]*w[16+i*16+j];
    b[j]=fmaxf(s*0.25f,0.f);
  }
  #pragma unroll
  for(int j=0;j<16;++j){
    float s=0.f;
    #pragma unroll
    for(int i=0;i<16;++i) s+=b[i]*w[272+i*16+j];
    h[j]=fmaxf(s*0.25f,0.f);
  }
}

// h[e][16] for all edges; FC0-2 weights staged in LDS
__global__ __launch_bounds__(256) void hmlp_k(const float* __restrict__ emb,
    const float* __restrict__ wfc, float* __restrict__ H, int E){
  __shared__ float sw[528];
  for(int t=threadIdx.x;t<528;t+=256) sw[t]=wfc[t];
  __syncthreads();
  int e=blockIdx.x*256+threadIdx.x; if(e>=E) return;
  float h[16]; mlp16(emb[e], sw, h);
  float4* H4=(float4*)(H+(size_t)e*16);
  #pragma unroll
  for(int q=0;q<4;++q) H4[q]=make_float4(h[4*q],h[4*q+1],h[4*q+2],h[4*q+3]);
}

// hb[3000][16] for the 3 bond sets
__global__ __launch_bounds__(256) void hb_k(const float* __restrict__ emb,
    const float* __restrict__ wfc, const int* __restrict__ i0,
    const int* __restrict__ i1, const int* __restrict__ i2,
    float* __restrict__ HB){
  __shared__ float sw[528];
  for(int t=threadIdx.x;t<528;t+=256) sw[t]=wfc[t];
  __syncthreads();
  int t=blockIdx.x*256+threadIdx.x; if(t>=3*N_BONDS) return;
  const int* ind = (t<N_BONDS)? i0 : (t<2*N_BONDS? i1 : i2);
  int ie = ind[t%N_BONDS];
  float h[16]; mlp16(emb[ie], sw, h);
  float4* H4=(float4*)(HB+(size_t)t*16);
  #pragma unroll
  for(int q=0;q<4;++q) H4[q]=make_float4(h[4*q],h[4*q+1],h[4*q+2],h[4*q+3]);
}

// =====================================================================
// C[E x N] = 0.25 * A[E x 16] * B[16 x N]   (0.25 = fc last layer /sqrt(16))
// Tile: 64 rows x 64 cols per block; 256 threads (4 row-quarters x 64 cols)
// =====================================================================
__global__ __launch_bounds__(256) void gemm16_k(const float* __restrict__ A,
    const float* __restrict__ B, float* __restrict__ C, int E, int N){
  __shared__ float As[64][16];
  int tid=threadIdx.x;
  int et=blockIdx.x, ct=blockIdx.y;
  for(int t=tid;t<64*16;t+=256){
    int r=t/16, i=t%16;
    int e=et*64+r;
    As[r][i]=(e<E)? A[(size_t)e*16+i] : 0.f;
  }
  __syncthreads();
  int col=ct*64+(tid&63);
  int eq=tid>>6;
  bool colok = col<N;
  float Breg[16];
  #pragma unroll
  for(int i=0;i<16;++i) Breg[i]= colok? B[(size_t)i*N+col]*0.25f : 0.f;
  #pragma unroll 4
  for(int es=0;es<16;++es){
    int e=et*64+eq*16+es;
    if (e>=E) break;
    float acc=0.f;
    #pragma unroll
    for(int i=0;i<16;++i) acc+=As[eq*16+es][i]*Breg[i];
    if (colok) C[(size_t)e*N+col]=acc;
  }
}

// =====================================================================
// Edge conv 1 consumer: weights precomputed (ww1[e][48])
// =====================================================================
template<int D,int BO,int OO,int P>
__device__ __forceinline__ void tp1b_path(const float* __restrict__ b,
    const float* __restrict__ wr, float a0, float a1, float scale, float* __restrict__ outp){
  #pragma unroll
  for(int w8=0;w8<8;++w8){
    float s=(wr[P*16+w8]*a0 + wr[P*16+8+w8]*a1)*scale;
    #pragma unroll
    for(int j=0;j<D;++j) atomicAdd(&outp[OO+w8*D+j], s*b[BO+j]);
  }
}

__global__ __launch_bounds__(256) void edge1b_k(const float* __restrict__ x1,
    const float* __restrict__ sh, const float* __restrict__ ww1,
    const int* __restrict__ esrc, const int* __restrict__ edst,
    const float* __restrict__ nnb, float* __restrict__ xout){
  int e=blockIdx.x*256+threadIdx.x; if(e>=N_EDGES) return;
  float inv = rsqrtf(nnb[0]);
  const float c = 0.70710678f*inv;
  const float* wr = ww1 + (size_t)e*48;
  int src=esrc[e], dst=edst[e];
  float a0=x1[2*src], a1=x1[2*src+1];
  float b[9];
  #pragma unroll
  for(int j=0;j<9;++j) b[j]=sh[(size_t)e*9+j];
  float* outp = xout + (size_t)dst*72;
  tp1b_path<1,0,0,0>(b,wr,a0,a1,c,outp);
  tp1b_path<3,1,8,1>(b,wr,a0,a1,c,outp);
  tp1b_path<5,4,32,2>(b,wr,a0,a1,c,outp);
}

// =====================================================================
// Block-diagonal linear (8ch per slice), /sqrt(8), optional tanh
// =====================================================================
template<int L>
__device__ __forceinline__ void diag_block(float* Xs, const float* __restrict__ w, bool dotanh){
  constexpr int D=2*L+1;
  const float r8=0.35355339f;
  float in[8*D];
  #pragma unroll
  for(int t=0;t<8*D;++t) in[t]=Xs[t];
  #pragma unroll
  for(int v=0;v<8;++v){
    #pragma unroll
    for(int i=0;i<D;++i){
      float acc=0.f;
      #pragma unroll
      for(int u=0;u<8;++u) acc+=in[u*D+i]*w[u*8+v];
      acc*=r8;
      Xs[v*D+i]= dotanh? tanhf(acc):acc;
    }
  }
}

__global__ __launch_bounds__(256) void lin2_k(float* __restrict__ x, const float* __restrict__ w){
  int n=blockIdx.x*256+threadIdx.x; if(n>=N_NODES) return;
  float* X=x+(size_t)n*72;
  diag_block<0>(X,    w,     true);
  diag_block<1>(X+8,  w+64,  false);
  diag_block<2>(X+32, w+128, false);
}

__global__ __launch_bounds__(256) void lin3_k(float* __restrict__ x, const float* __restrict__ w){
  int n=blockIdx.x*256+threadIdx.x; if(n>=N_NODES) return;
  float* X=x+(size_t)n*144;
  diag_block<0>(X,     w,     true);
  diag_block<0>(X+8,   w+64,  true);
  diag_block<1>(X+16,  w+128, false);
  diag_block<1>(X+40,  w+192, false);
  diag_block<2>(X+64,  w+256, false);
  diag_block<2>(X+104, w+320, false);
}

// =====================================================================
// Edge conv 2 consumer: TP(MID1 x SH -> MID2), weights precomputed
// =====================================================================
template<int L1,int L2,int LO,int AO,int BO,int WB>
__device__ __forceinline__ void tp2b_path(const float* __restrict__ A, const float* __restrict__ b,
    const float* __restrict__ cg, const float4* __restrict__ wr4, float* __restrict__ ch){
  constexpr int D1=2*L1+1, D2=2*L2+1, DN=2*LO+1;
  const float* C = cg + ((L1*3+L2)*3+LO)*125;
  float t[8][DN];
  #pragma unroll
  for(int u=0;u<8;++u){
    #pragma unroll
    for(int k=0;k<DN;++k) t[u][k]=0.f;
  }
  #pragma unroll
  for(int i=0;i<D1;++i){
    #pragma unroll
    for(int j=0;j<D2;++j){
      #pragma unroll
      for(int k=0;k<DN;++k){
        float cv=C[(i*D2+j)*DN+k];
        if (cv!=0.f){
          float cb=cv*b[BO+j];
          #pragma unroll
          for(int u=0;u<8;++u) t[u][k]+=A[AO+u*D1+i]*cb;
        }
      }
    }
  }
  #pragma unroll
  for(int u=0;u<8;++u){
    float4 wa=wr4[(WB>>2)+u*2], wb4=wr4[(WB>>2)+u*2+1];
    float wwv[8]={wa.x,wa.y,wa.z,wa.w,wb4.x,wb4.y,wb4.z,wb4.w};
    #pragma unroll
    for(int w=0;w<8;++w){
      #pragma unroll
      for(int k=0;k<DN;++k) ch[w*DN+k]+=wwv[w]*t[u][k];
    }
  }
}

__global__ __launch_bounds__(256) void edge2b_k(const float* __restrict__ xn,
    const float* __restrict__ sh, const float* __restrict__ ww2,
    const int* __restrict__ esrc, const int* __restrict__ edst,
    const float* __restrict__ nnb, const float* __restrict__ cg,
    float* __restrict__ xout, int e0, int e1){
  int e=e0+blockIdx.x*256+threadIdx.x; if(e>=e1) return;
  float inv = rsqrtf(nnb[0]);
  int src=esrc[e], dst=edst[e];
  const float* A = xn + (size_t)src*72;
  const float4* wr4 = (const float4*)(ww2 + (size_t)(e-e0)*960);
  float b[9];
  #pragma unroll
  for(int j=0;j<9;++j) b[j]=sh[(size_t)e*9+j];
  float* out = xout + (size_t)dst*144;
  { // 0e (off 0), fan 24
    float ch[8]={0};
    tp2b_path<0,0,0,0,0,0>(A,b,cg,wr4,ch);
    tp2b_path<1,1,0,8,1,256>(A,b,cg,wr4,ch);
    tp2b_path<2,2,0,32,4,768>(A,b,cg,wr4,ch);
    float f=rsqrtf(24.f)*inv;
    #pragma unroll
    for(int t=0;t<8;++t) atomicAdd(&out[0+t], ch[t]*f);
  }
  { // 1e (off 16), fan 16
    float ch[24]={0};
    tp2b_path<1,1,1,8,1,320>(A,b,cg,wr4,ch);
    tp2b_path<2,2,1,32,4,832>(A,b,cg,wr4,ch);
    float f=rsqrtf(16.f)*inv;
    #pragma unroll
    for(int t=0;t<24;++t) atomicAdd(&out[16+t], ch[t]*f);
  }
  { // 1o (off 40), fan 32
    float ch[24]={0};
    tp2b_path<0,1,1,0,1,64>(A,b,cg,wr4,ch);
    tp2b_path<1,0,1,8,0,192>(A,b,cg,wr4,ch);
    tp2b_path<1,2,1,8,4,448>(A,b,cg,wr4,ch);
    tp2b_path<2,1,1,32,1,640>(A,b,cg,wr4,ch);
    float f=rsqrtf(32.f)*inv;
    #pragma unroll
    for(int t=0;t<24;++t) atomicAdd(&out[40+t], ch[t]*f);
  }
  { // 2e (off 64), fan 32
    float ch[40]={0};
    tp2b_path<0,2,2,0,4,128>(A,b,cg,wr4,ch);
    tp2b_path<1,1,2,8,1,384>(A,b,cg,wr4,ch);
    tp2b_path<2,0,2,32,0,576>(A,b,cg,wr4,ch);
    tp2b_path<2,2,2,32,4,896>(A,b,cg,wr4,ch);
    float f=rsqrtf(32.f)*inv;
    #pragma unroll
    for(int t=0;t<40;++t) atomicAdd(&out[64+t], ch[t]*f);
  }
  { // 2o (off 104), fan 16
    float ch[40]={0};
    tp2b_path<1,2,2,8,4,512>(A,b,cg,wr4,ch);
    tp2b_path<2,1,2,32,1,704>(A,b,cg,wr4,ch);
    float f=rsqrtf(16.f)*inv;
    #pragma unroll
    for(int t=0;t<40;++t) atomicAdd(&out[104+t], ch[t]*f);
  }
}

// =====================================================================
// Generic irrep linear from MID2-layout input (fan=8 per slice)
// =====================================================================
struct IrS{ short off,m,l,p; };
__device__ const IrS SL_MID2[6]={{0,8,0,1},{8,8,0,-1},{16,8,1,1},{40,8,1,-1},{64,8,2,1},{104,8,2,-1}};
__device__ const IrS SL_HH[6]={{0,4,0,1},{4,2,1,-1},{10,2,1,-1},{16,1,0,1},{17,1,1,1},{20,1,2,1}};
__device__ const IrS SL_CC[34]={{0,9,0,1},{9,6,1,-1},{27,3,2,1},{42,6,1,-1},
 {60,1,0,1},{61,1,1,1},{64,1,2,1},{69,1,0,1},{70,1,1,1},{73,1,2,1},
 {78,1,0,1},{79,1,1,1},{82,1,2,1},{87,1,0,1},{88,1,1,1},{91,1,2,1},
 {96,1,1,-1},{99,1,2,-1},{104,1,3,-1},{111,1,1,-1},{114,1,2,-1},{119,1,3,-1},
 {126,3,2,1},{141,1,1,-1},{144,1,2,-1},{149,1,3,-1},{156,1,1,-1},{159,1,2,-1},{164,1,3,-1},
 {171,1,0,1},{172,1,1,1},{175,1,2,1},{180,1,3,1},{187,1,4,1}};
__device__ const IrS SL_CH[13]={{0,6,0,1},{6,3,1,-1},{15,4,1,-1},{27,1,0,1},{28,1,1,1},{31,1,2,1},
 {36,1,0,1},{37,1,1,1},{40,1,2,1},{45,2,2,1},{55,1,1,-1},{58,1,2,-1},{63,1,3,-1}};

__device__ void lin_out(const float* __restrict__ x, bool act16, const float* __restrict__ w,
                        const IrS* so, int no, int dim,
                        void* out, size_t base, bool f32o, float scale){
  float tx[16];
  if (act16){
    #pragma unroll
    for(int i=0;i<16;++i) tx[i]=tanhf(x[i]);
  }
  for(int i=0;i<dim;++i) stout(out, base+i, 0.f, f32o);
  int woff=0;
  for(int a=0;a<6;++a){
    int la=SL_MID2[a].l, pa=SL_MID2[a].p, oa=SL_MID2[a].off;
    int d=2*la+1;
    for(int bI=0;bI<no;++bI){
      if (so[bI].l!=la || so[bI].p!=pa) continue;
      int mo=so[bI].m;
      float f = 0.35355339f*scale;
      for(int v=0;v<mo;++v){
        for(int i=0;i<d;++i){
          float acc=0.f;
          for(int u=0;u<8;++u){
            int idx=oa+u*d+i;
            float xv=(act16 && idx<16)? tx[idx] : x[idx];
            acc+=xv*w[woff+u*mo+v];
          }
          stout(out, base+so[bI].off+v*d+i, acc*f, f32o);
        }
      }
      woff+=8*mo;
    }
  }
}

// =====================================================================
// Node outputs: nH, nC, screen
// =====================================================================
__global__ __launch_bounds__(256) void node_out_k(const float* __restrict__ x,
    const float* __restrict__ wC, const float* __restrict__ wH,
    const float* __restrict__ ws1, const float* __restrict__ ws2,
    void* out, const int* __restrict__ flag){
  int n=blockIdx.x*256+threadIdx.x; if(n>=N_NODES) return;
  bool f32o = (*flag)!=0;
  const float* X = x + (size_t)n*144;
  lin_out(X,false,wH,SL_HH,6,25,   out, (size_t)n*25, f32o, 0.2f);
  lin_out(X,false,wC,SL_CC,34,196, out, 250000 + (size_t)n*196, f32o, 0.2f);
  const float r8=0.35355339f, r32=0.17677670f;
  float t0[32];
  for(int v=0;v<32;++v){
    float acc=0.f;
    #pragma unroll
    for(int u=0;u<8;++u) acc+=X[u]*ws1[u*32+v];
    t0[v]=tanhf(acc*r8);
  }
  float t2[5];
  #pragma unroll
  for(int i=0;i<5;++i){
    float acc=0.f;
    #pragma unroll
    for(int u=0;u<8;++u) acc+=X[64+u*5+i]*ws1[256+u];
    t2[i]=acc*r8;
  }
  size_t sb = 2501000 + (size_t)n*6;
  float acc=0.f;
  for(int v=0;v<32;++v) acc+=t0[v]*ws2[v];
  stout(out, sb, acc*r32, f32o);
  float w2e=ws2[32];
  #pragma unroll
  for(int i=0;i<5;++i) stout(out, sb+1+i, t2[i]*w2e, f32o);
}

// =====================================================================
// Bond TP consumer: one wave per bond, weights precomputed (wwb rows)
// =====================================================================
template<int L1,int L2,int LO>
__device__ __forceinline__ void bond_pathb(const float* sa,int ao,const float* sb,int bo,
    const float* __restrict__ cg, const float* __restrict__ wrow, int wbase, float invfan,
    float* sP, float* sF, int oo, int lane){
  constexpr int D1=2*L1+1, D2=2*L2+1, DN=2*LO+1;
  const float* C = cg + ((L1*3+L2)*3+LO)*125;
  int u=lane>>3, v=lane&7;
  float P[DN];
  #pragma unroll
  for(int k=0;k<DN;++k) P[k]=0.f;
  #pragma unroll
  for(int i=0;i<D1;++i){
    float avv=sa[ao+u*D1+i];
    #pragma unroll
    for(int j=0;j<D2;++j){
      float ab=avv*sb[bo+v*D2+j];
      #pragma unroll
      for(int k=0;k<DN;++k){
        float cv=C[(i*D2+j)*DN+k];
        if(cv!=0.f) P[k]+=ab*cv;
      }
    }
  }
  #pragma unroll
  for(int k=0;k<DN;++k) sP[lane*5+k]=P[k];
  __syncthreads();
  int v2=lane>>3, w=lane&7;
  float acc[DN];
  #pragma unroll
  for(int k=0;k<DN;++k) acc[k]=0.f;
  #pragma unroll
  for(int u2=0;u2<8;++u2){
    float ww = wrow[wbase + u2*64 + lane]; // lane = v2*8+w, coalesced
    #pragma unroll
    for(int k=0;k<DN;++k) acc[k]+=ww*sP[(u2*8+v2)*5+k];
  }
  #pragma unroll
  for(int k=0;k<DN;++k){
    acc[k]+=__shfl_xor(acc[k],8,64);
    acc[k]+=__shfl_xor(acc[k],16,64);
    acc[k]+=__shfl_xor(acc[k],32,64);
  }
  if (v2==0){
    #pragma unroll
    for(int k=0;k<DN;++k) sF[oo+w*DN+k]+=acc[k]*invfan;
  }
  __syncthreads();
}

__global__ __launch_bounds__(256) void bond_tpb_k(const float* __restrict__ xn,
    const float* __restrict__ wwb,
    const int* __restrict__ esrc, const int* __restrict__ edst,
    const int* __restrict__ ind, const float* __restrict__ cg,
    float* __restrict__ Fout, int b0, int b1){
  __shared__ float sA[4][144], sB[4][144], sF[4][144], sP[4][320];
  int wid=threadIdx.x>>6, lane=threadIdx.x&63;
  int e=b0+blockIdx.x*4+wid;
  bool act = (e<b1);
  int ee = act? e : b0;
  int ie=ind[ee];
  int src=esrc[ie], dst=edst[ie];
  for(int t=lane;t<144;t+=64){
    sA[wid][t]=xn[(size_t)src*144+t];
    sB[wid][t]=xn[(size_t)dst*144+t];
    sF[wid][t]=0.f;
  }
  const float* wrow = wwb + (size_t)(ee-b0)*30720;
  __syncthreads();
  const int SL_L[6]={0,0,1,1,2,2};
  const int SL_P[6]={1,-1,1,-1,1,-1};
  const int SL_O[6]={0,8,16,40,64,104};
  const float fi0=rsqrtf(384.f), fi1=rsqrtf(768.f);
  int wbase=0;
  for(int s1=0;s1<6;++s1){
    for(int s2=0;s2<6;++s2){
      for(int so=0;so<6;++so){
        int l1=SL_L[s1], l2=SL_L[s2], lo=SL_L[so];
        if (SL_P[so]!=SL_P[s1]*SL_P[s2]) continue;
        if (lo<iabs(l1-l2) || lo>l1+l2) continue;
        int code=l1*9+l2*3+lo;
        float* a=sA[wid]; float* bb=sB[wid]; float* P=sP[wid]; float* F=sF[wid];
        int ao=SL_O[s1], bo=SL_O[s2], oo=SL_O[so];
        float fv = (lo==0)? fi0 : fi1;
        switch(code){
          case 0:  bond_pathb<0,0,0>(a,ao,bb,bo,cg,wrow,wbase,fv,P,F,oo,lane); break;
          case 4:  bond_pathb<0,1,1>(a,ao,bb,bo,cg,wrow,wbase,fv,P,F,oo,lane); break;
          case 8:  bond_pathb<0,2,2>(a,ao,bb,bo,cg,wrow,wbase,fv,P,F,oo,lane); break;
          case 10: bond_pathb<1,0,1>(a,ao,bb,bo,cg,wrow,wbase,fv,P,F,oo,lane); break;
          case 12: bond_pathb<1,1,0>(a,ao,bb,bo,cg,wrow,wbase,fv,P,F,oo,lane); break;
          case 13: bond_pathb<1,1,1>(a,ao,bb,bo,cg,wrow,wbase,fv,P,F,oo,lane); break;
          case 14: bond_pathb<1,1,2>(a,ao,bb,bo,cg,wrow,wbase,fv,P,F,oo,lane); break;
          case 16: bond_pathb<1,2,1>(a,ao,bb,bo,cg,wrow,wbase,fv,P,F,oo,lane); break;
          case 17: bond_pathb<1,2,2>(a,ao,bb,bo,cg,wrow,wbase,fv,P,F,oo,lane); break;
          case 20: bond_pathb<2,0,2>(a,ao,bb,bo,cg,wrow,wbase,fv,P,F,oo,lane); break;
          case 22: bond_pathb<2,1,1>(a,ao,bb,bo,cg,wrow,wbase,fv,P,F,oo,lane); break;
          case 23: bond_pathb<2,1,2>(a,ao,bb,bo,cg,wrow,wbase,fv,P,F,oo,lane); break;
          case 24: bond_pathb<2,2,0>(a,ao,bb,bo,cg,wrow,wbase,fv,P,F,oo,lane); break;
          case 25: bond_pathb<2,2,1>(a,ao,bb,bo,cg,wrow,wbase,fv,P,F,oo,lane); break;
          case 26: bond_pathb<2,2,2>(a,ao,bb,bo,cg,wrow,wbase,fv,P,F,oo,lane); break;
        }
        wbase+=512;
      }
    }
  }
  __syncthreads();
  if (act){
    for(int t=lane;t<144;t+=64) Fout[(size_t)e*144+t]=sF[wid][t];
  }
}

// =====================================================================
// Bond outputs: eXX = lin(act(F)) * 0.2 ; gap = L_G2(tanh(L_G1(F_raw)))
// =====================================================================
__global__ __launch_bounds__(256) void bond_out_k(const float* __restrict__ F,
    const float* __restrict__ wlin, int tbl, void* out, size_t baseE,
    const float* __restrict__ wg1, const float* __restrict__ wg2,
    size_t baseG, const int* __restrict__ flag){
  int n=blockIdx.x*256+threadIdx.x; if(n>=N_BONDS) return;
  bool f32o = (*flag)!=0;
  const float* X=F+(size_t)n*144;
  const IrS* so; int no; int dim;
  if(tbl==0){so=SL_HH;no=6;dim=25;}
  else if(tbl==1){so=SL_CC;no=34;dim=196;}
  else {so=SL_CH;no=13;dim=70;}
  lin_out(X,true,wlin,so,no,dim,out,baseE+(size_t)n*dim,f32o,0.2f);
  const float r8=0.35355339f, r32=0.17677670f;
  float g[32];
  for(int v=0;v<32;++v){
    float acc=0.f;
    #pragma unroll
    for(int u=0;u<8;++u) acc+=X[u]*wg1[u*32+v];
    g[v]=tanhf(acc*r8);
  }
  #pragma unroll
  for(int c=0;c<3;++c){
    float acc=0.f;
    for(int v=0;v<32;++v) acc+=g[v]*wg2[v*3+c];
    stout(out, baseG+(size_t)n*3+c, acc*r32, f32o);
  }
}

// =====================================================================
extern "C" void kernel_launch(void* const* d_in, const int* in_sizes, int n_in,
                              void* d_out, int out_size, void* d_ws, size_t ws_size,
                              hipStream_t stream){
  const int* esrc=(const int*)d_in[19];
  const int* edst=(const int*)d_in[20];
  const int* iHH =(const int*)d_in[21];
  const int* iCC =(const int*)d_in[22];
  const int* iCH =(const int*)d_in[23];
  float* ws=(float*)d_ws;
  int* flag=(int*)d_ws;

  size_t off=16;
  auto alloc=[&](size_t n){ size_t o=off; off+=(n+15)&~(size_t)15; return o; };
  size_t o_cg = alloc(27*125);
  size_t o_st[19];
  for(int i=0;i<19;++i) o_st[i]=alloc((size_t)in_sizes[i]);
  size_t o_x1  = alloc(20000);
  size_t o_xM1 = alloc(720000);
  size_t o_xM2 = alloc(1440000);
  size_t o_F0  = alloc(144000);
  size_t o_F1  = alloc(144000);
  size_t o_F2  = alloc(144000);
  size_t o_h1  = alloc((size_t)N_EDGES*16);
  size_t o_h2  = alloc((size_t)N_EDGES*16);
  size_t o_hb  = alloc((size_t)3*N_BONDS*16);
  size_t o_ww1 = alloc((size_t)N_EDGES*48);
  // remaining space -> shared weight buffer (chunked use)
  size_t remain = (ws_size/4 > off)? (ws_size/4 - off) : 0;
  size_t o_wb  = off;
  // chunk sizes limited by available buffer
  int bchunk = (int)min((size_t)N_BONDS, remain/30720);
  int echunk = (int)min((size_t)25000, remain/960);
  if (bchunk<1) bchunk=1;
  if (echunk<256) echunk=256;

  float* cg  = ws+o_cg;
  float* x1  = ws+o_x1;
  float* xM1 = ws+o_xM1;
  float* xM2 = ws+o_xM2;
  float* F0  = ws+o_F0;
  float* F1  = ws+o_F1;
  float* F2  = ws+o_F2;
  float* h1  = ws+o_h1;
  float* h2  = ws+o_h2;
  float* hb  = ws+o_hb;
  float* ww1 = ws+o_ww1;
  float* wbuf= ws+o_wb;

  CvtArgs ca;
  for(int i=0;i<19;++i){ ca.src[i]=d_in[i]; ca.dst[i]=ws+o_st[i]; ca.n[i]=in_sizes[i]; }
  const float* sh     = ws+o_st[1];
  const float* emb    = ws+o_st[2];
  const float* nnb    = ws+o_st[3];
  const float* f_in   = ws+o_st[0];
  const float* w_lin1 = ws+o_st[4];
  const float* w_lin2 = ws+o_st[5];
  const float* w_lin3 = ws+o_st[6];
  const float* w_linCC= ws+o_st[7];
  const float* w_linHH= ws+o_st[8];
  const float* w_linCH= ws+o_st[9];
  const float* w_linC = ws+o_st[10];
  const float* w_linH = ws+o_st[11];
  const float* w_s1   = ws+o_st[12];
  const float* w_s2   = ws+o_st[13];
  const float* w_g1   = ws+o_st[14];
  const float* w_g2   = ws+o_st[15];
  const float* w_fc1  = ws+o_st[16];
  const float* w_fc2  = ws+o_st[17];
  const float* w_fcb  = ws+o_st[18];

  detect_k<<<1,1,0,stream>>>((const unsigned short*)d_in[3], flag);
  convert_k<<<512,256,0,stream>>>(ca, flag);
  hipMemsetAsync(xM1, 0, 720000*sizeof(float), stream);
  hipMemsetAsync(xM2, 0, 1440000*sizeof(float), stream);

  cg_init_k<<<27,128,0,stream>>>(cg);
  nodeA_k<<<40,256,0,stream>>>(f_in,w_lin1,x1);
  hmlp_k<<<391,256,0,stream>>>(emb, w_fc1, h1, N_EDGES);
  hmlp_k<<<391,256,0,stream>>>(emb, w_fc2, h2, N_EDGES);
  hb_k<<<12,256,0,stream>>>(emb, w_fcb, iHH, iCC, iCH, hb);

  // edge conv 1
  gemm16_k<<<dim3(1563,1),256,0,stream>>>(h1, w_fc1+528, ww1, N_EDGES, 48);
  edge1b_k<<<391,256,0,stream>>>(x1,sh,ww1,esrc,edst,nnb,xM1);
  lin2_k<<<40,256,0,stream>>>(xM1,w_lin2);

  // edge conv 2, chunked weight GEMM + consumer
  for(int e0=0;e0<N_EDGES;e0+=echunk){
    int E=min(echunk, N_EDGES-e0);
    gemm16_k<<<dim3((E+63)/64,15),256,0,stream>>>(h2+(size_t)e0*16, w_fc2+528, wbuf, E, 960);
    edge2b_k<<<(E+255)/256,256,0,stream>>>(xM1,sh,wbuf,esrc,edst,nnb,cg,xM2,e0,e0+E);
  }
  lin3_k<<<40,256,0,stream>>>(xM2,w_lin3);
  node_out_k<<<40,256,0,stream>>>(xM2,w_linC,w_linH,w_s1,w_s2,d_out,flag);

  // bond TPs, chunked
  for(int s=0;s<3;++s){
    const int* ind = (s==0)? iHH : (s==1)? iCC : iCH;
    float* F = (s==0)? F0 : (s==1)? F1 : F2;
    for(int b0=0;b0<N_BONDS;b0+=bchunk){
      int Bc=min(bchunk, N_BONDS-b0);
      gemm16_k<<<dim3((Bc+63)/64,480),256,0,stream>>>(hb+((size_t)s*N_BONDS+b0)*16, w_fcb+528, wbuf, Bc, 30720);
      bond_tpb_k<<<(Bc+3)/4,256,0,stream>>>(xM2,wbuf,esrc,edst,ind,cg,F,b0,b0+Bc);
    }
  }
  // outputs: 0:nH@0 1:nC@250000 2:eHH@2210000 3:eCH@2235000 4:eCC@2305000
  //          5:screen@2501000 6:gapCC@2561000 7:gapHH@2564000 8:gapCH@2567000
  bond_out_k<<<4,256,0,stream>>>(F0,w_linHH,0,d_out,2210000,w_g1,w_g2,2564000,flag);
  bond_out_k<<<4,256,0,stream>>>(F1,w_linCC,1,d_out,2305000,w_g1,w_g2,2561000,flag);
  bond_out_k<<<4,256,0,stream>>>(F2,w_linCH,2,d_out,2235000,w_g1,w_g2,2567000,flag);
}

// Round 4
// 2836.061 us; speedup vs baseline: 1.8497x; 1.1334x over previous
//
#include <hip/hip_runtime.h>
#include <hip/hip_bf16.h>

typedef __hip_bfloat16 bf16_t;

#define N_NODES 10000
#define N_EDGES 100000
#define N_BONDS 1000

__device__ __forceinline__ float bf2f(bf16_t v){ return __bfloat162float(v); }
__device__ __forceinline__ bf16_t f2bf(float v){ return __float2bfloat16(v); }
__device__ __forceinline__ int iabs(int x){ return x<0?-x:x; }

__device__ __forceinline__ void stout(void* out, size_t idx, float v, bool f32o){
  if (f32o) ((float*)out)[idx]=v;
  else      ((bf16_t*)out)[idx]=f2bf(v);
}

// =====================================================================
// Dtype detection: num_neighbors == 10.0 always. bf16 -> u16[0]==0x4120.
// =====================================================================
__global__ void detect_k(const unsigned short* nnb_raw, int* flag){
  *flag = (nnb_raw[0]==0x4120) ? 0 : 1;
}

struct CvtArgs {
  const void* src[19];
  float* dst[19];
  int n[19];
};

__global__ __launch_bounds__(256) void convert_k(CvtArgs a, const int* flag){
  bool f32 = (*flag)!=0;
  int tid = blockIdx.x*256+threadIdx.x;
  int nth = gridDim.x*256;
  for(int t=0;t<19;++t){
    int n=a.n[t];
    float* d=a.dst[t];
    if (f32){
      const float* s=(const float*)a.src[t];
      for(int i=tid;i<n;i+=nth) d[i]=s[i];
    } else {
      const bf16_t* s=(const bf16_t*)a.src[t];
      for(int i=tid;i<n;i+=nth) d[i]=bf2f(s[i]);
    }
  }
}

// =====================================================================
// CSR build: edges sorted by destination node
// =====================================================================
__global__ __launch_bounds__(256) void csr_count_k(const int* __restrict__ edst, int* __restrict__ cnt){
  int e=blockIdx.x*256+threadIdx.x; if(e>=N_EDGES) return;
  atomicAdd(&cnt[edst[e]],1);
}

__global__ __launch_bounds__(256) void csr_scan_k(const int* __restrict__ cnt,
    int* __restrict__ rowptr, int* __restrict__ pos){
  __shared__ int ssum[256];
  int t=threadIdx.x;
  int base=t*40;
  int s=0;
  for(int i=0;i<40;++i){ int idx=base+i; s += (idx<N_NODES)? cnt[idx]:0; }
  ssum[t]=s; __syncthreads();
  if(t==0){ int run=0; for(int i=0;i<256;++i){ int v=ssum[i]; ssum[i]=run; run+=v; } }
  __syncthreads();
  int run=ssum[t];
  for(int i=0;i<40;++i){
    int idx=base+i;
    if(idx<N_NODES){ rowptr[idx]=run; pos[idx]=run; run+=cnt[idx]; }
  }
  if(t==255) rowptr[N_NODES]=run;
}

__global__ __launch_bounds__(256) void csr_scatter_k(const int* __restrict__ edst,
    int* __restrict__ pos, int* __restrict__ sorted){
  int e=blockIdx.x*256+threadIdx.x; if(e>=N_EDGES) return;
  int p=atomicAdd(&pos[edst[e]],1);
  sorted[p]=e;
}

// =====================================================================
// CG tables (device, double precision, exact replica of reference)
// =====================================================================
__device__ __forceinline__ double dfact(int n){
  const double F[11]={1.,1.,2.,6.,24.,120.,720.,5040.,40320.,362880.,3628800.};
  return F[n];
}

__device__ double cgc_d(int j1,int m1,int j2,int m2,int j3,int m3){
  if (m1+m2!=m3) return 0.0;
  double pre = sqrt((double)(2*j3+1)*dfact(j3+j1-j2)*dfact(j3-j1+j2)*dfact(j1+j2-j3)/dfact(j1+j2+j3+1));
  pre *= sqrt(dfact(j3+m3)*dfact(j3-m3)*dfact(j1-m1)*dfact(j1+m1)*dfact(j2-m2)*dfact(j2+m2));
  int k0 = max(0, max(j2-j3-m1, j1-j3+m2));
  int k1 = min(j1+j2-j3, min(j1-m1, j2+m2));
  double s=0.0;
  for(int k=k0;k<=k1;++k)
    s += ((k&1)?-1.0:1.0)/(dfact(k)*dfact(j1+j2-j3-k)*dfact(j1-m1-k)*dfact(j2+m2-k)*dfact(j3-j2+m1+k)*dfact(j3-j1-m2+k));
  return pre*s;
}

__device__ void c2r_d(int l,int a,int m,double&re,double&im){
  re=0.0; im=0.0;
  const double r2 = 0.7071067811865475244;
  int mu = a-l;
  if (mu==0){ if (m==l) re=1.0; return; }
  if (mu>0){
    if (m==l+mu) re = (mu&1)? -r2 : r2;
    else if (m==l-mu) re = r2;
  } else {
    int nu=-mu;
    if (m==l-nu) im = r2;
    else if (m==l+nu) im = (nu&1)? r2 : -r2;
  }
}

__global__ __launch_bounds__(128) void cg_init_k(float* cg){
  int b=blockIdx.x;
  int l1=b/9, l2=(b/3)%3, l3=b%3;
  if (l3 < iabs(l1-l2) || l3 > l1+l2) return;
  int n1=2*l1+1,n2=2*l2+1,n3=2*l3+1,n=n1*n2*n3;
  __shared__ double sRe[125], sIm[125];
  __shared__ int sPick;
  int t=threadIdx.x;
  if (t<n){
    int a=t/(n2*n3), bb=(t/n3)%n2, c=t%n3;
    double re=0.0, im=0.0;
    for(int m1=0;m1<n1;++m1){
      double q1r,q1i; c2r_d(l1,a,m1,q1r,q1i);
      if (q1r==0.0 && q1i==0.0) continue;
      for(int m2=0;m2<n2;++m2){
        double q2r,q2i; c2r_d(l2,bb,m2,q2r,q2i);
        if (q2r==0.0 && q2i==0.0) continue;
        int m3=(m1-l1)+(m2-l2)+l3;
        if (m3<0||m3>=n3) continue;
        double q3r,q3i; c2r_d(l3,c,m3,q3r,q3i); q3i=-q3i;
        double C = cgc_d(l1,m1-l1,l2,m2-l2,l3,m3-l3);
        if (C==0.0) continue;
        double ar = q1r*q2r - q1i*q2i;
        double ai = q1r*q2i + q1i*q2r;
        re += (ar*q3r - ai*q3i)*C;
        im += (ar*q3i + ai*q3r)*C;
      }
    }
    sRe[t]=re; sIm[t]=im;
  }
  __syncthreads();
  if (t==0){
    double s1=0.0,s2=0.0;
    for(int i=0;i<n;++i){ s1+=fabs(sRe[i]); s2+=fabs(sIm[i]); }
    sPick = (s1>=s2)?1:0;
  }
  __syncthreads();
  if (t<n) cg[b*125+t] = (float)(sPick? sRe[t] : sIm[t]);
}

// =====================================================================
// Stage A: x1 = tanh(f_in @ W(2x2) / sqrt(2))
// =====================================================================
__global__ __launch_bounds__(256) void nodeA_k(const float* __restrict__ fin,
                                               const float* __restrict__ w,
                                               float* __restrict__ x1){
  int n=blockIdx.x*256+threadIdx.x; if(n>=N_NODES) return;
  float f0=fin[2*n], f1=fin[2*n+1];
  const float r2=0.70710678f;
  x1[2*n]   = tanhf((f0*w[0]+f1*w[2])*r2);
  x1[2*n+1] = tanhf((f0*w[1]+f1*w[3])*r2);
}

// MLP [1,16,16,16] layers 0..2 of fc_apply (relu after each)
__device__ __forceinline__ void mlp16(float e, const float* w, float* h){
  float a[16];
  #pragma unroll
  for(int j=0;j<16;++j) a[j]=fmaxf(e*w[j],0.f);
  float b[16];
  #pragma unroll
  for(int j=0;j<16;++j){
    float s=0.f;
    #pragma unroll
    for(int i=0;i<16;++i) s+=a[i]*w[16+i*16+j];
    b[j]=fmaxf(s*0.25f,0.f);
  }
  #pragma unroll
  for(int j=0;j<16;++j){
    float s=0.f;
    #pragma unroll
    for(int i=0;i<16;++i) s+=b[i]*w[272+i*16+j];
    h[j]=fmaxf(s*0.25f,0.f);
  }
}

__global__ __launch_bounds__(256) void hmlp_k(const float* __restrict__ emb,
    const float* __restrict__ wfc, float* __restrict__ H, int E){
  __shared__ float sw[528];
  for(int t=threadIdx.x;t<528;t+=256) sw[t]=wfc[t];
  __syncthreads();
  int e=blockIdx.x*256+threadIdx.x; if(e>=E) return;
  float h[16]; mlp16(emb[e], sw, h);
  float4* H4=(float4*)(H+(size_t)e*16);
  #pragma unroll
  for(int q=0;q<4;++q) H4[q]=make_float4(h[4*q],h[4*q+1],h[4*q+2],h[4*q+3]);
}

__global__ __launch_bounds__(256) void hb_k(const float* __restrict__ emb,
    const float* __restrict__ wfc, const int* __restrict__ i0,
    const int* __restrict__ i1, const int* __restrict__ i2,
    float* __restrict__ HB){
  __shared__ float sw[528];
  for(int t=threadIdx.x;t<528;t+=256) sw[t]=wfc[t];
  __syncthreads();
  int t=blockIdx.x*256+threadIdx.x; if(t>=3*N_BONDS) return;
  const int* ind = (t<N_BONDS)? i0 : (t<2*N_BONDS? i1 : i2);
  int ie = ind[t%N_BONDS];
  float h[16]; mlp16(emb[ie], sw, h);
  float4* H4=(float4*)(HB+(size_t)t*16);
  #pragma unroll
  for(int q=0;q<4;++q) H4[q]=make_float4(h[4*q],h[4*q+1],h[4*q+2],h[4*q+3]);
}

// =====================================================================
// C[r x N] = 0.25 * A[idx(r) x 16] * B[16 x N]
// =====================================================================
__global__ __launch_bounds__(256) void gemm16_k(const float* __restrict__ A,
    const float* __restrict__ B, float* __restrict__ C, int E, int N,
    const int* __restrict__ idx){
  __shared__ float As[64][16];
  int tid=threadIdx.x;
  int et=blockIdx.x, ct=blockIdx.y;
  for(int t=tid;t<64*16;t+=256){
    int r=t/16, i=t%16;
    int e=et*64+r;
    int ea = (e<E)? (idx? idx[e] : e) : -1;
    As[r][i]=(ea>=0)? A[(size_t)ea*16+i] : 0.f;
  }
  __syncthreads();
  int col=ct*64+(tid&63);
  int eq=tid>>6;
  bool colok = col<N;
  float Breg[16];
  #pragma unroll
  for(int i=0;i<16;++i) Breg[i]= colok? B[(size_t)i*N+col]*0.25f : 0.f;
  #pragma unroll 4
  for(int es=0;es<16;++es){
    int e=et*64+eq*16+es;
    if (e>=E) break;
    float acc=0.f;
    #pragma unroll
    for(int i=0;i<16;++i) acc+=As[eq*16+es][i]*Breg[i];
    if (colok) C[(size_t)e*N+col]=acc;
  }
}

// =====================================================================
// Edge conv 1 GATHER: one thread per node, no atomics.
// =====================================================================
__global__ __launch_bounds__(256) void edge1g_k(const float* __restrict__ x1,
    const float* __restrict__ sh, const float* __restrict__ ww1,
    const int* __restrict__ esrc, const int* __restrict__ sorted,
    const int* __restrict__ rowptr, const float* __restrict__ nnb,
    float* __restrict__ xout){
  int n=blockIdx.x*256+threadIdx.x; if(n>=N_NODES) return;
  float inv = rsqrtf(nnb[0]);
  const float c = 0.70710678f*inv;
  float acc[72];
  #pragma unroll
  for(int t=0;t<72;++t) acc[t]=0.f;
  int r0=rowptr[n], r1=rowptr[n+1];
  for(int r=r0;r<r1;++r){
    int e=sorted[r];
    int src=esrc[e];
    float a0=x1[2*src], a1=x1[2*src+1];
    const float4* wr4=(const float4*)(ww1+(size_t)e*48);
    float wr[48];
    #pragma unroll
    for(int q=0;q<12;++q){ float4 v=wr4[q]; wr[4*q]=v.x; wr[4*q+1]=v.y; wr[4*q+2]=v.z; wr[4*q+3]=v.w; }
    float b[9];
    #pragma unroll
    for(int j=0;j<9;++j) b[j]=sh[(size_t)e*9+j];
    #pragma unroll
    for(int w8=0;w8<8;++w8){
      float s0=wr[w8]*a0+wr[8+w8]*a1;
      acc[w8]+=s0*b[0];
      float s1=wr[16+w8]*a0+wr[24+w8]*a1;
      #pragma unroll
      for(int j=0;j<3;++j) acc[8+w8*3+j]+=s1*b[1+j];
      float s2=wr[32+w8]*a0+wr[40+w8]*a1;
      #pragma unroll
      for(int j=0;j<5;++j) acc[32+w8*5+j]+=s2*b[4+j];
    }
  }
  float* o=xout+(size_t)n*72;
  #pragma unroll
  for(int t=0;t<72;++t) o[t]=acc[t]*c;
}

// =====================================================================
// Block-diagonal linear (8ch per slice), /sqrt(8), optional tanh
// =====================================================================
template<int L>
__device__ __forceinline__ void diag_block(float* Xs, const float* __restrict__ w, bool dotanh){
  constexpr int D=2*L+1;
  const float r8=0.35355339f;
  float in[8*D];
  #pragma unroll
  for(int t=0;t<8*D;++t) in[t]=Xs[t];
  #pragma unroll
  for(int v=0;v<8;++v){
    #pragma unroll
    for(int i=0;i<D;++i){
      float acc=0.f;
      #pragma unroll
      for(int u=0;u<8;++u) acc+=in[u*D+i]*w[u*8+v];
      acc*=r8;
      Xs[v*D+i]= dotanh? tanhf(acc):acc;
    }
  }
}

__global__ __launch_bounds__(256) void lin2_k(float* __restrict__ x, const float* __restrict__ w){
  int n=blockIdx.x*256+threadIdx.x; if(n>=N_NODES) return;
  float* X=x+(size_t)n*72;
  diag_block<0>(X,    w,     true);
  diag_block<1>(X+8,  w+64,  false);
  diag_block<2>(X+32, w+128, false);
}

__global__ __launch_bounds__(256) void lin3_k(float* __restrict__ x, const float* __restrict__ w){
  int n=blockIdx.x*256+threadIdx.x; if(n>=N_NODES) return;
  float* X=x+(size_t)n*144;
  diag_block<0>(X,     w,     true);
  diag_block<0>(X+8,   w+64,  true);
  diag_block<1>(X+16,  w+128, false);
  diag_block<1>(X+40,  w+192, false);
  diag_block<2>(X+64,  w+256, false);
  diag_block<2>(X+104, w+320, false);
}

// =====================================================================
// Edge conv 2 GATHER: one wave per node. lane=(u=lane>>3, w=lane&7).
// Weights pre-materialized in CSR-sorted row order.
// Per-lane acc layout: 0e@0, 0o@1(unused), 1e@2..4, 1o@5..7, 2e@8..12, 2o@13..17
// =====================================================================
template<int L1,int L2,int LO,int AO,int BO,int WB,int SLOT>
__device__ __forceinline__ void e2g_path(const float* __restrict__ A,
    const float* __restrict__ b, const float* __restrict__ cg,
    const float* __restrict__ wrow, int u, int lane, float* acc){
  constexpr int D1=2*L1+1, D2=2*L2+1, DN=2*LO+1;
  const float* C = cg + ((L1*3+L2)*3+LO)*125;
  float P[DN];
  #pragma unroll
  for(int k=0;k<DN;++k) P[k]=0.f;
  #pragma unroll
  for(int i=0;i<D1;++i){
    float av=A[AO+u*D1+i];
    #pragma unroll
    for(int j=0;j<D2;++j){
      float ab=av*b[BO+j];
      #pragma unroll
      for(int k=0;k<DN;++k){
        float cv=C[(i*D2+j)*DN+k];
        if(cv!=0.f) P[k]+=ab*cv;
      }
    }
  }
  float wv = wrow[WB + lane];
  #pragma unroll
  for(int k=0;k<DN;++k) acc[SLOT+k]+=wv*P[k];
}

__global__ __launch_bounds__(256) void edge2g_k(const float* __restrict__ xn,
    const float* __restrict__ sh, const float* __restrict__ wbuf,
    const int* __restrict__ esrc, const int* __restrict__ sorted,
    const int* __restrict__ rowptr, const float* __restrict__ nnb,
    const float* __restrict__ cg, float* __restrict__ xout){
  int wid=threadIdx.x>>6, lane=threadIdx.x&63;
  int n=blockIdx.x*4+wid; if(n>=N_NODES) return;
  int u=lane>>3, w=lane&7;
  float inv = rsqrtf(nnb[0]);
  float acc[18];
  #pragma unroll
  for(int t=0;t<18;++t) acc[t]=0.f;
  int r0=rowptr[n], r1=rowptr[n+1];
  for(int r=r0;r<r1;++r){
    int e=sorted[r];
    const float* A = xn + (size_t)esrc[e]*72;
    float b[9];
    #pragma unroll
    for(int j=0;j<9;++j) b[j]=sh[(size_t)e*9+j];
    const float* wrow = wbuf + (size_t)r*960;
    e2g_path<0,0,0, 0,0,   0, 0>(A,b,cg,wrow,u,lane,acc);
    e2g_path<1,1,0, 8,1, 256, 0>(A,b,cg,wrow,u,lane,acc);
    e2g_path<2,2,0,32,4, 768, 0>(A,b,cg,wrow,u,lane,acc);
    e2g_path<1,1,1, 8,1, 320, 2>(A,b,cg,wrow,u,lane,acc);
    e2g_path<2,2,1,32,4, 832, 2>(A,b,cg,wrow,u,lane,acc);
    e2g_path<0,1,1, 0,1,  64, 5>(A,b,cg,wrow,u,lane,acc);
    e2g_path<1,0,1, 8,0, 192, 5>(A,b,cg,wrow,u,lane,acc);
    e2g_path<1,2,1, 8,4, 448, 5>(A,b,cg,wrow,u,lane,acc);
    e2g_path<2,1,1,32,1, 640, 5>(A,b,cg,wrow,u,lane,acc);
    e2g_path<0,2,2, 0,4, 128, 8>(A,b,cg,wrow,u,lane,acc);
    e2g_path<1,1,2, 8,1, 384, 8>(A,b,cg,wrow,u,lane,acc);
    e2g_path<2,0,2,32,0, 576, 8>(A,b,cg,wrow,u,lane,acc);
    e2g_path<2,2,2,32,4, 896, 8>(A,b,cg,wrow,u,lane,acc);
    e2g_path<1,2,2, 8,4, 512,13>(A,b,cg,wrow,u,lane,acc);
    e2g_path<2,1,2,32,1, 704,13>(A,b,cg,wrow,u,lane,acc);
  }
  #pragma unroll
  for(int t=0;t<18;++t){
    acc[t]+=__shfl_xor(acc[t],8,64);
    acc[t]+=__shfl_xor(acc[t],16,64);
    acc[t]+=__shfl_xor(acc[t],32,64);
  }
  if (lane<8){
    float* o = xout + (size_t)n*144;
    float f0 =rsqrtf(24.f)*inv;
    float f1e=rsqrtf(16.f)*inv;
    float f1o=rsqrtf(32.f)*inv;
    float f2e=rsqrtf(32.f)*inv;
    float f2o=rsqrtf(16.f)*inv;
    o[0+w]=acc[0]*f0;
    o[8+w]=0.f;
    #pragma unroll
    for(int k=0;k<3;++k) o[16+w*3+k]=acc[2+k]*f1e;
    #pragma unroll
    for(int k=0;k<3;++k) o[40+w*3+k]=acc[5+k]*f1o;
    #pragma unroll
    for(int k=0;k<5;++k) o[64+w*5+k]=acc[8+k]*f2e;
    #pragma unroll
    for(int k=0;k<5;++k) o[104+w*5+k]=acc[13+k]*f2o;
  }
}

// =====================================================================
// FALLBACK consumers (atomic-based, used only if ws too small)
// =====================================================================
template<int D,int BO,int OO,int P>
__device__ __forceinline__ void tp1b_path(const float* __restrict__ b,
    const float* __restrict__ wr, float a0, float a1, float scale, float* __restrict__ outp){
  #pragma unroll
  for(int w8=0;w8<8;++w8){
    float s=(wr[P*16+w8]*a0 + wr[P*16+8+w8]*a1)*scale;
    #pragma unroll
    for(int j=0;j<D;++j) atomicAdd(&outp[OO+w8*D+j], s*b[BO+j]);
  }
}

__global__ __launch_bounds__(256) void edge1b_k(const float* __restrict__ x1,
    const float* __restrict__ sh, const float* __restrict__ ww1,
    const int* __restrict__ esrc, const int* __restrict__ edst,
    const float* __restrict__ nnb, float* __restrict__ xout){
  int e=blockIdx.x*256+threadIdx.x; if(e>=N_EDGES) return;
  float inv = rsqrtf(nnb[0]);
  const float c = 0.70710678f*inv;
  const float* wr = ww1 + (size_t)e*48;
  int src=esrc[e], dst=edst[e];
  float a0=x1[2*src], a1=x1[2*src+1];
  float b[9];
  #pragma unroll
  for(int j=0;j<9;++j) b[j]=sh[(size_t)e*9+j];
  float* outp = xout + (size_t)dst*72;
  tp1b_path<1,0,0,0>(b,wr,a0,a1,c,outp);
  tp1b_path<3,1,8,1>(b,wr,a0,a1,c,outp);
  tp1b_path<5,4,32,2>(b,wr,a0,a1,c,outp);
}

template<int L1,int L2,int LO,int AO,int BO,int WB>
__device__ __forceinline__ void tp2b_path(const float* __restrict__ A, const float* __restrict__ b,
    const float* __restrict__ cg, const float4* __restrict__ wr4, float* __restrict__ ch){
  constexpr int D1=2*L1+1, D2=2*L2+1, DN=2*LO+1;
  const float* C = cg + ((L1*3+L2)*3+LO)*125;
  float t[8][DN];
  #pragma unroll
  for(int u=0;u<8;++u){
    #pragma unroll
    for(int k=0;k<DN;++k) t[u][k]=0.f;
  }
  #pragma unroll
  for(int i=0;i<D1;++i){
    #pragma unroll
    for(int j=0;j<D2;++j){
      #pragma unroll
      for(int k=0;k<DN;++k){
        float cv=C[(i*D2+j)*DN+k];
        if (cv!=0.f){
          float cb=cv*b[BO+j];
          #pragma unroll
          for(int u=0;u<8;++u) t[u][k]+=A[AO+u*D1+i]*cb;
        }
      }
    }
  }
  #pragma unroll
  for(int u=0;u<8;++u){
    float4 wa=wr4[(WB>>2)+u*2], wb4=wr4[(WB>>2)+u*2+1];
    float wwv[8]={wa.x,wa.y,wa.z,wa.w,wb4.x,wb4.y,wb4.z,wb4.w};
    #pragma unroll
    for(int w=0;w<8;++w){
      #pragma unroll
      for(int k=0;k<DN;++k) ch[w*DN+k]+=wwv[w]*t[u][k];
    }
  }
}

__global__ __launch_bounds__(256) void edge2b_k(const float* __restrict__ xn,
    const float* __restrict__ sh, const float* __restrict__ ww2,
    const int* __restrict__ esrc, const int* __restrict__ edst,
    const float* __restrict__ nnb, const float* __restrict__ cg,
    float* __restrict__ xout, int e0, int e1){
  int e=e0+blockIdx.x*256+threadIdx.x; if(e>=e1) return;
  float inv = rsqrtf(nnb[0]);
  int src=esrc[e], dst=edst[e];
  const float* A = xn + (size_t)src*72;
  const float4* wr4 = (const float4*)(ww2 + (size_t)(e-e0)*960);
  float b[9];
  #pragma unroll
  for(int j=0;j<9;++j) b[j]=sh[(size_t)e*9+j];
  float* out = xout + (size_t)dst*144;
  {
    float ch[8]={0};
    tp2b_path<0,0,0,0,0,0>(A,b,cg,wr4,ch);
    tp2b_path<1,1,0,8,1,256>(A,b,cg,wr4,ch);
    tp2b_path<2,2,0,32,4,768>(A,b,cg,wr4,ch);
    float f=rsqrtf(24.f)*inv;
    #pragma unroll
    for(int t=0;t<8;++t) atomicAdd(&out[0+t], ch[t]*f);
  }
  {
    float ch[24]={0};
    tp2b_path<1,1,1,8,1,320>(A,b,cg,wr4,ch);
    tp2b_path<2,2,1,32,4,832>(A,b,cg,wr4,ch);
    float f=rsqrtf(16.f)*inv;
    #pragma unroll
    for(int t=0;t<24;++t) atomicAdd(&out[16+t], ch[t]*f);
  }
  {
    float ch[24]={0};
    tp2b_path<0,1,1,0,1,64>(A,b,cg,wr4,ch);
    tp2b_path<1,0,1,8,0,192>(A,b,cg,wr4,ch);
    tp2b_path<1,2,1,8,4,448>(A,b,cg,wr4,ch);
    tp2b_path<2,1,1,32,1,640>(A,b,cg,wr4,ch);
    float f=rsqrtf(32.f)*inv;
    #pragma unroll
    for(int t=0;t<24;++t) atomicAdd(&out[40+t], ch[t]*f);
  }
  {
    float ch[40]={0};
    tp2b_path<0,2,2,0,4,128>(A,b,cg,wr4,ch);
    tp2b_path<1,1,2,8,1,384>(A,b,cg,wr4,ch);
    tp2b_path<2,0,2,32,0,576>(A,b,cg,wr4,ch);
    tp2b_path<2,2,2,32,4,896>(A,b,cg,wr4,ch);
    float f=rsqrtf(32.f)*inv;
    #pragma unroll
    for(int t=0;t<40;++t) atomicAdd(&out[64+t], ch[t]*f);
  }
  {
    float ch[40]={0};
    tp2b_path<1,2,2,8,4,512>(A,b,cg,wr4,ch);
    tp2b_path<2,1,2,32,1,704>(A,b,cg,wr4,ch);
    float f=rsqrtf(16.f)*inv;
    #pragma unroll
    for(int t=0;t<40;++t) atomicAdd(&out[104+t], ch[t]*f);
  }
}

// =====================================================================
// Irrep linear (fan=8 per slice); zero-fills unmatched output slices.
// =====================================================================
struct IrS{ short off,m,l,p; };
__device__ const IrS SL_MID2[6]={{0,8,0,1},{8,8,0,-1},{16,8,1,1},{40,8,1,-1},{64,8,2,1},{104,8,2,-1}};
__device__ const IrS SL_HH[6]={{0,4,0,1},{4,2,1,-1},{10,2,1,-1},{16,1,0,1},{17,1,1,1},{20,1,2,1}};
__device__ const IrS SL_CC[34]={{0,9,0,1},{9,6,1,-1},{27,3,2,1},{42,6,1,-1},
 {60,1,0,1},{61,1,1,1},{64,1,2,1},{69,1,0,1},{70,1,1,1},{73,1,2,1},
 {78,1,0,1},{79,1,1,1},{82,1,2,1},{87,1,0,1},{88,1,1,1},{91,1,2,1},
 {96,1,1,-1},{99,1,2,-1},{104,1,3,-1},{111,1,1,-1},{114,1,2,-1},{119,1,3,-1},
 {126,3,2,1},{141,1,1,-1},{144,1,2,-1},{149,1,3,-1},{156,1,1,-1},{159,1,2,-1},{164,1,3,-1},
 {171,1,0,1},{172,1,1,1},{175,1,2,1},{180,1,3,1},{187,1,4,1}};
__device__ const IrS SL_CH[13]={{0,6,0,1},{6,3,1,-1},{15,4,1,-1},{27,1,0,1},{28,1,1,1},{31,1,2,1},
 {36,1,0,1},{37,1,1,1},{40,1,2,1},{45,2,2,1},{55,1,1,-1},{58,1,2,-1},{63,1,3,-1}};

__device__ void lin_out(const float* __restrict__ x, bool act16, const float* __restrict__ w,
                        const IrS* so, int no, int dim,
                        void* out, size_t base, bool f32o, float scale){
  float tx[16];
  if (act16){
    #pragma unroll
    for(int i=0;i<16;++i) tx[i]=tanhf(x[i]);
  }
  for(int i=0;i<dim;++i) stout(out, base+i, 0.f, f32o);
  int woff=0;
  for(int a=0;a<6;++a){
    int la=SL_MID2[a].l, pa=SL_MID2[a].p, oa=SL_MID2[a].off;
    int d=2*la+1;
    for(int bI=0;bI<no;++bI){
      if (so[bI].l!=la || so[bI].p!=pa) continue;
      int mo=so[bI].m;
      float f = 0.35355339f*scale;
      for(int v=0;v<mo;++v){
        for(int i=0;i<d;++i){
          float acc=0.f;
          for(int u=0;u<8;++u){
            int idx=oa+u*d+i;
            float xv=(act16 && idx<16)? tx[idx] : x[idx];
            acc+=xv*w[woff+u*mo+v];
          }
          stout(out, base+so[bI].off+v*d+i, acc*f, f32o);
        }
      }
      woff+=8*mo;
    }
  }
}

// =====================================================================
// Node outputs: nH, nC, screen
// =====================================================================
__global__ __launch_bounds__(256) void node_out_k(const float* __restrict__ x,
    const float* __restrict__ wC, const float* __restrict__ wH,
    const float* __restrict__ ws1, const float* __restrict__ ws2,
    void* out, const int* __restrict__ flag){
  int n=blockIdx.x*256+threadIdx.x; if(n>=N_NODES) return;
  bool f32o = (*flag)!=0;
  const float* X = x + (size_t)n*144;
  lin_out(X,false,wH,SL_HH,6,25,   out, (size_t)n*25, f32o, 0.2f);
  lin_out(X,false,wC,SL_CC,34,196, out, 250000 + (size_t)n*196, f32o, 0.2f);
  const float r8=0.35355339f, r32=0.17677670f;
  float t0[32];
  for(int v=0;v<32;++v){
    float acc=0.f;
    #pragma unroll
    for(int u=0;u<8;++u) acc+=X[u]*ws1[u*32+v];
    t0[v]=tanhf(acc*r8);
  }
  float t2[5];
  #pragma unroll
  for(int i=0;i<5;++i){
    float acc=0.f;
    #pragma unroll
    for(int u=0;u<8;++u) acc+=X[64+u*5+i]*ws1[256+u];
    t2[i]=acc*r8;
  }
  size_t sb = 2501000 + (size_t)n*6;
  float acc=0.f;
  for(int v=0;v<32;++v) acc+=t0[v]*ws2[v];
  stout(out, sb, acc*r32, f32o);
  float w2e=ws2[32];
  #pragma unroll
  for(int i=0;i<5;++i) stout(out, sb+1+i, t2[i]*w2e, f32o);
}

// =====================================================================
// Bond TP: one wave per bond, precomputed weights (coalesced reads)
// =====================================================================
template<int L1,int L2,int LO>
__device__ __forceinline__ void bond_pathb(const float* sa,int ao,const float* sb,int bo,
    const float* __restrict__ cg, const float* __restrict__ wrow, int wbase, float invfan,
    float* sP, float* sF, int oo, int lane){
  constexpr int D1=2*L1+1, D2=2*L2+1, DN=2*LO+1;
  const float* C = cg + ((L1*3+L2)*3+LO)*125;
  int u=lane>>3, v=lane&7;
  float P[DN];
  #pragma unroll
  for(int k=0;k<DN;++k) P[k]=0.f;
  #pragma unroll
  for(int i=0;i<D1;++i){
    float avv=sa[ao+u*D1+i];
    #pragma unroll
    for(int j=0;j<D2;++j){
      float ab=avv*sb[bo+v*D2+j];
      #pragma unroll
      for(int k=0;k<DN;++k){
        float cv=C[(i*D2+j)*DN+k];
        if(cv!=0.f) P[k]+=ab*cv;
      }
    }
  }
  #pragma unroll
  for(int k=0;k<DN;++k) sP[lane*5+k]=P[k];
  __syncthreads();
  int v2=lane>>3, w=lane&7;
  float acc[DN];
  #pragma unroll
  for(int k=0;k<DN;++k) acc[k]=0.f;
  #pragma unroll
  for(int u2=0;u2<8;++u2){
    float ww = wrow[wbase + u2*64 + lane];
    #pragma unroll
    for(int k=0;k<DN;++k) acc[k]+=ww*sP[(u2*8+v2)*5+k];
  }
  #pragma unroll
  for(int k=0;k<DN;++k){
    acc[k]+=__shfl_xor(acc[k],8,64);
    acc[k]+=__shfl_xor(acc[k],16,64);
    acc[k]+=__shfl_xor(acc[k],32,64);
  }
  if (v2==0){
    #pragma unroll
    for(int k=0;k<DN;++k) sF[oo+w*DN+k]+=acc[k]*invfan;
  }
  __syncthreads();
}

__device__ __forceinline__ void bond_body(const float* xn, const float* wrow,
    int src, int dst, const float* cg, float* Fout, int wid, int lane,
    float sA[4][144], float sB[4][144], float sF[4][144], float sP[4][320], bool act){
  for(int t=lane;t<144;t+=64){
    sA[wid][t]=xn[(size_t)src*144+t];
    sB[wid][t]=xn[(size_t)dst*144+t];
    sF[wid][t]=0.f;
  }
  __syncthreads();
  const int SL_L[6]={0,0,1,1,2,2};
  const int SL_P[6]={1,-1,1,-1,1,-1};
  const int SL_O[6]={0,8,16,40,64,104};
  const float fi0=rsqrtf(384.f), fi1=rsqrtf(768.f);
  int wbase=0;
  for(int s1=0;s1<6;++s1){
    for(int s2=0;s2<6;++s2){
      for(int so=0;so<6;++so){
        int l1=SL_L[s1], l2=SL_L[s2], lo=SL_L[so];
        if (SL_P[so]!=SL_P[s1]*SL_P[s2]) continue;
        if (lo<iabs(l1-l2) || lo>l1+l2) continue;
        int code=l1*9+l2*3+lo;
        float* a=sA[wid]; float* bb=sB[wid]; float* P=sP[wid]; float* F=sF[wid];
        int ao=SL_O[s1], bo=SL_O[s2], oo=SL_O[so];
        float fv = (lo==0)? fi0 : fi1;
        switch(code){
          case 0:  bond_pathb<0,0,0>(a,ao,bb,bo,cg,wrow,wbase,fv,P,F,oo,lane); break;
          case 4:  bond_pathb<0,1,1>(a,ao,bb,bo,cg,wrow,wbase,fv,P,F,oo,lane); break;
          case 8:  bond_pathb<0,2,2>(a,ao,bb,bo,cg,wrow,wbase,fv,P,F,oo,lane); break;
          case 10: bond_pathb<1,0,1>(a,ao,bb,bo,cg,wrow,wbase,fv,P,F,oo,lane); break;
          case 12: bond_pathb<1,1,0>(a,ao,bb,bo,cg,wrow,wbase,fv,P,F,oo,lane); break;
          case 13: bond_pathb<1,1,1>(a,ao,bb,bo,cg,wrow,wbase,fv,P,F,oo,lane); break;
          case 14: bond_pathb<1,1,2>(a,ao,bb,bo,cg,wrow,wbase,fv,P,F,oo,lane); break;
          case 16: bond_pathb<1,2,1>(a,ao,bb,bo,cg,wrow,wbase,fv,P,F,oo,lane); break;
          case 17: bond_pathb<1,2,2>(a,ao,bb,bo,cg,wrow,wbase,fv,P,F,oo,lane); break;
          case 20: bond_pathb<2,0,2>(a,ao,bb,bo,cg,wrow,wbase,fv,P,F,oo,lane); break;
          case 22: bond_pathb<2,1,1>(a,ao,bb,bo,cg,wrow,wbase,fv,P,F,oo,lane); break;
          case 23: bond_pathb<2,1,2>(a,ao,bb,bo,cg,wrow,wbase,fv,P,F,oo,lane); break;
          case 24: bond_pathb<2,2,0>(a,ao,bb,bo,cg,wrow,wbase,fv,P,F,oo,lane); break;
          case 25: bond_pathb<2,2,1>(a,ao,bb,bo,cg,wrow,wbase,fv,P,F,oo,lane); break;
          case 26: bond_pathb<2,2,2>(a,ao,bb,bo,cg,wrow,wbase,fv,P,F,oo,lane); break;
        }
        wbase+=512;
      }
    }
  }
  __syncthreads();
  if (act){
    for(int t=lane;t<144;t+=64) Fout[t]=sF[wid][t];
  }
  __syncthreads();
}

// merged consumer over all 3 bond sets (gb = 0..2999)
__global__ __launch_bounds__(256) void bond_tpm_k(const float* __restrict__ xn,
    const float* __restrict__ wwb,
    const int* __restrict__ esrc, const int* __restrict__ edst,
    const int* __restrict__ i0, const int* __restrict__ i1, const int* __restrict__ i2,
    const float* __restrict__ cg,
    float* __restrict__ F0, float* __restrict__ F1, float* __restrict__ F2){
  __shared__ float sA[4][144], sB[4][144], sF[4][144], sP[4][320];
  int wid=threadIdx.x>>6, lane=threadIdx.x&63;
  int gb=blockIdx.x*4+wid;
  int s=gb/N_BONDS, bi=gb%N_BONDS;
  const int* ind = (s==0)? i0 : (s==1)? i1 : i2;
  float* F = (s==0)? F0 : (s==1)? F1 : F2;
  int ie=ind[bi];
  bond_body(xn, wwb+(size_t)gb*30720, esrc[ie], edst[ie], cg,
            F+(size_t)bi*144, wid, lane, sA,sB,sF,sP, true);
}

// fallback: chunked single-set consumer
__global__ __launch_bounds__(256) void bond_tpb_k(const float* __restrict__ xn,
    const float* __restrict__ wwb,
    const int* __restrict__ esrc, const int* __restrict__ edst,
    const int* __restrict__ ind, const float* __restrict__ cg,
    float* __restrict__ Fout, int b0, int b1){
  __shared__ float sA[4][144], sB[4][144], sF[4][144], sP[4][320];
  int wid=threadIdx.x>>6, lane=threadIdx.x&63;
  int e=b0+blockIdx.x*4+wid;
  bool act=(e<b1);
  int ee=act? e:b0;
  int ie=ind[ee];
  bond_body(xn, wwb+(size_t)(ee-b0)*30720, esrc[ie], edst[ie], cg,
            Fout+(size_t)e*144, wid, lane, sA,sB,sF,sP, act);
}

// =====================================================================
// Bond outputs
// =====================================================================
__global__ __launch_bounds__(256) void bond_out_k(const float* __restrict__ F,
    const float* __restrict__ wlin, int tbl, void* out, size_t baseE,
    const float* __restrict__ wg1, const float* __restrict__ wg2,
    size_t baseG, const int* __restrict__ flag){
  int n=blockIdx.x*256+threadIdx.x; if(n>=N_BONDS) return;
  bool f32o = (*flag)!=0;
  const float* X=F+(size_t)n*144;
  const IrS* so; int no; int dim;
  if(tbl==0){so=SL_HH;no=6;dim=25;}
  else if(tbl==1){so=SL_CC;no=34;dim=196;}
  else {so=SL_CH;no=13;dim=70;}
  lin_out(X,true,wlin,so,no,dim,out,baseE+(size_t)n*dim,f32o,0.2f);
  const float r8=0.35355339f, r32=0.17677670f;
  float g[32];
  for(int v=0;v<32;++v){
    float acc=0.f;
    #pragma unroll
    for(int u=0;u<8;++u) acc+=X[u]*wg1[u*32+v];
    g[v]=tanhf(acc*r8);
  }
  #pragma unroll
  for(int c=0;c<3;++c){
    float acc=0.f;
    for(int v=0;v<32;++v) acc+=g[v]*wg2[v*3+c];
    stout(out, baseG+(size_t)n*3+c, acc*r32, f32o);
  }
}

// =====================================================================
extern "C" void kernel_launch(void* const* d_in, const int* in_sizes, int n_in,
                              void* d_out, int out_size, void* d_ws, size_t ws_size,
                              hipStream_t stream){
  const int* esrc=(const int*)d_in[19];
  const int* edst=(const int*)d_in[20];
  const int* iHH =(const int*)d_in[21];
  const int* iCC =(const int*)d_in[22];
  const int* iCH =(const int*)d_in[23];
  float* ws=(float*)d_ws;
  int* flag=(int*)d_ws;

  size_t off=16;
  auto alloc=[&](size_t n){ size_t o=off; off+=(n+15)&~(size_t)15; return o; };
  size_t o_cg = alloc(27*125);
  size_t o_st[19];
  for(int i=0;i<19;++i) o_st[i]=alloc((size_t)in_sizes[i]);
  size_t o_x1  = alloc(20000);
  size_t o_xM1 = alloc(720000);
  size_t o_xM2 = alloc(1440000);
  size_t o_F0  = alloc(144000);
  size_t o_F1  = alloc(144000);
  size_t o_F2  = alloc(144000);
  size_t o_h1  = alloc((size_t)N_EDGES*16);
  size_t o_h2  = alloc((size_t)N_EDGES*16);
  size_t o_hb  = alloc((size_t)3*N_BONDS*16);
  size_t o_ww1 = alloc((size_t)N_EDGES*48);
  size_t o_cnt = alloc(10016);
  size_t o_rp  = alloc(10016);
  size_t o_pos = alloc(10016);
  size_t o_srt = alloc(N_EDGES);
  size_t o_big = off;

  const size_t BIG_NEED = 96000000; // max(100000*960, 3000*30720)
  size_t avail = ws_size/4;
  bool bigpath = (avail >= o_big + BIG_NEED);

  float* cg  = ws+o_cg;
  float* x1  = ws+o_x1;
  float* xM1 = ws+o_xM1;
  float* xM2 = ws+o_xM2;
  float* F0  = ws+o_F0;
  float* F1  = ws+o_F1;
  float* F2  = ws+o_F2;
  float* h1  = ws+o_h1;
  float* h2  = ws+o_h2;
  float* hb  = ws+o_hb;
  float* ww1 = ws+o_ww1;
  int* cnt   = (int*)(ws+o_cnt);
  int* rowptr= (int*)(ws+o_rp);
  int* pos   = (int*)(ws+o_pos);
  int* sorted= (int*)(ws+o_srt);
  float* wbuf= ws+o_big;

  CvtArgs ca;
  for(int i=0;i<19;++i){ ca.src[i]=d_in[i]; ca.dst[i]=ws+o_st[i]; ca.n[i]=in_sizes[i]; }
  const float* f_in   = ws+o_st[0];
  const float* sh     = ws+o_st[1];
  const float* emb    = ws+o_st[2];
  const float* nnb    = ws+o_st[3];
  const float* w_lin1 = ws+o_st[4];
  const float* w_lin2 = ws+o_st[5];
  const float* w_lin3 = ws+o_st[6];
  const float* w_linCC= ws+o_st[7];
  const float* w_linHH= ws+o_st[8];
  const float* w_linCH= ws+o_st[9];
  const float* w_linC = ws+o_st[10];
  const float* w_linH = ws+o_st[11];
  const float* w_s1   = ws+o_st[12];
  const float* w_s2   = ws+o_st[13];
  const float* w_g1   = ws+o_st[14];
  const float* w_g2   = ws+o_st[15];
  const float* w_fc1  = ws+o_st[16];
  const float* w_fc2  = ws+o_st[17];
  const float* w_fcb  = ws+o_st[18];

  detect_k<<<1,1,0,stream>>>((const unsigned short*)d_in[3], flag);
  convert_k<<<512,256,0,stream>>>(ca, flag);
  cg_init_k<<<27,128,0,stream>>>(cg);
  nodeA_k<<<40,256,0,stream>>>(f_in,w_lin1,x1);
  hmlp_k<<<391,256,0,stream>>>(emb, w_fc1, h1, N_EDGES);
  hmlp_k<<<391,256,0,stream>>>(emb, w_fc2, h2, N_EDGES);
  hb_k<<<12,256,0,stream>>>(emb, w_fcb, iHH, iCC, iCH, hb);
  gemm16_k<<<dim3(1563,1),256,0,stream>>>(h1, w_fc1+528, ww1, N_EDGES, 48, (const int*)nullptr);

  if (bigpath){
    // CSR by destination
    hipMemsetAsync(cnt, 0, 10000*sizeof(int), stream);
    csr_count_k<<<391,256,0,stream>>>(edst, cnt);
    csr_scan_k<<<1,256,0,stream>>>(cnt, rowptr, pos);
    csr_scatter_k<<<391,256,0,stream>>>(edst, pos, sorted);
    // edge conv 1 (gather)
    edge1g_k<<<40,256,0,stream>>>(x1,sh,ww1,esrc,sorted,rowptr,nnb,xM1);
    lin2_k<<<40,256,0,stream>>>(xM1,w_lin2);
    // edge conv 2: full weight materialization in CSR order + gather
    gemm16_k<<<dim3(1563,15),256,0,stream>>>(h2, w_fc2+528, wbuf, N_EDGES, 960, sorted);
    edge2g_k<<<2500,256,0,stream>>>(xM1,sh,wbuf,esrc,sorted,rowptr,nnb,cg,xM2);
    lin3_k<<<40,256,0,stream>>>(xM2,w_lin3);
    node_out_k<<<40,256,0,stream>>>(xM2,w_linC,w_linH,w_s1,w_s2,d_out,flag);
    // bonds: one GEMM (3000 x 30720) into same buffer + merged consumer
    gemm16_k<<<dim3(47,480),256,0,stream>>>(hb, w_fcb+528, wbuf, 3*N_BONDS, 30720, (const int*)nullptr);
    bond_tpm_k<<<750,256,0,stream>>>(xM2,wbuf,esrc,edst,iHH,iCC,iCH,cg,F0,F1,F2);
  } else {
    // fallback: atomic consumers + chunked weight buffers
    size_t remain = (avail > o_big)? (avail - o_big) : 0;
    int bchunk = (int)min((size_t)N_BONDS, remain/30720);
    int echunk = (int)min((size_t)25000, remain/960);
    if (bchunk<1) bchunk=1;
    if (echunk<256) echunk=256;
    hipMemsetAsync(xM1, 0, 720000*sizeof(float), stream);
    hipMemsetAsync(xM2, 0, 1440000*sizeof(float), stream);
    edge1b_k<<<391,256,0,stream>>>(x1,sh,ww1,esrc,edst,nnb,xM1);
    lin2_k<<<40,256,0,stream>>>(xM1,w_lin2);
    for(int e0=0;e0<N_EDGES;e0+=echunk){
      int E=min(echunk, N_EDGES-e0);
      gemm16_k<<<dim3((E+63)/64,15),256,0,stream>>>(h2+(size_t)e0*16, w_fc2+528, wbuf, E, 960, (const int*)nullptr);
      edge2b_k<<<(E+255)/256,256,0,stream>>>(xM1,sh,wbuf,esrc,edst,nnb,cg,xM2,e0,e0+E);
    }
    lin3_k<<<40,256,0,stream>>>(xM2,w_lin3);
    node_out_k<<<40,256,0,stream>>>(xM2,w_linC,w_linH,w_s1,w_s2,d_out,flag);
    for(int s=0;s<3;++s){
      const int* ind = (s==0)? iHH : (s==1)? iCC : iCH;
      float* F = (s==0)? F0 : (s==1)? F1 : F2;
      for(int b0=0;b0<N_BONDS;b0+=bchunk){
        int Bc=min(bchunk, N_BONDS-b0);
        gemm16_k<<<dim3((Bc+63)/64,480),256,0,stream>>>(hb+((size_t)s*N_BONDS+b0)*16, w_fcb+528, wbuf, Bc, 30720, (const int*)nullptr);
        bond_tpb_k<<<(Bc+3)/4,256,0,stream>>>(xM2,wbuf,esrc,edst,ind,cg,F,b0,b0+Bc);
      }
    }
  }
  // outputs: 0:nH@0 1:nC@250000 2:eHH@2210000 3:eCH@2235000 4:eCC@2305000
  //          5:screen@2501000 6:gapCC@2561000 7:gapHH@2564000 8:gapCH@2567000
  bond_out_k<<<4,256,0,stream>>>(F0,w_linHH,0,d_out,2210000,w_g1,w_g2,2564000,flag);
  bond_out_k<<<4,256,0,stream>>>(F1,w_linCC,1,d_out,2305000,w_g1,w_g2,2561000,flag);
  bond_out_k<<<4,256,0,stream>>>(F2,w_linCH,2,d_out,2235000,w_g1,w_g2,2567000,flag);
}

// Round 5
// 2365.611 us; speedup vs baseline: 2.2175x; 1.1989x over previous
//
#include <hip/hip_runtime.h>
#include <hip/hip_bf16.h>

typedef __hip_bfloat16 bf16_t;

#define N_NODES 10000
#define N_EDGES 100000
#define N_BONDS 1000

__device__ __forceinline__ float bf2f(bf16_t v){ return __bfloat162float(v); }
__device__ __forceinline__ bf16_t f2bf(float v){ return __float2bfloat16(v); }
__device__ __forceinline__ int iabs(int x){ return x<0?-x:x; }

__device__ __forceinline__ void stout(void* out, size_t idx, float v, bool f32o){
  if (f32o) ((float*)out)[idx]=v;
  else      ((bf16_t*)out)[idx]=f2bf(v);
}

// =====================================================================
// Dtype detection: num_neighbors == 10.0 always. bf16 -> u16[0]==0x4120.
// =====================================================================
__global__ void detect_k(const unsigned short* nnb_raw, int* flag){
  *flag = (nnb_raw[0]==0x4120) ? 0 : 1;
}

struct CvtArgs {
  const void* src[19];
  float* dst[19];
  int n[19];
};

__global__ __launch_bounds__(256) void convert_k(CvtArgs a, const int* flag){
  bool f32 = (*flag)!=0;
  int tid = blockIdx.x*256+threadIdx.x;
  int nth = gridDim.x*256;
  for(int t=0;t<19;++t){
    int n=a.n[t];
    float* d=a.dst[t];
    if (f32){
      const float* s=(const float*)a.src[t];
      for(int i=tid;i<n;i+=nth) d[i]=s[i];
    } else {
      const bf16_t* s=(const bf16_t*)a.src[t];
      for(int i=tid;i<n;i+=nth) d[i]=bf2f(s[i]);
    }
  }
}

// =====================================================================
// CSR build: edges sorted by destination node
// =====================================================================
__global__ __launch_bounds__(256) void csr_count_k(const int* __restrict__ edst, int* __restrict__ cnt){
  int e=blockIdx.x*256+threadIdx.x; if(e>=N_EDGES) return;
  atomicAdd(&cnt[edst[e]],1);
}

__global__ __launch_bounds__(256) void csr_scan_k(const int* __restrict__ cnt,
    int* __restrict__ rowptr, int* __restrict__ pos){
  __shared__ int ssum[256];
  int t=threadIdx.x;
  int base=t*40;
  int s=0;
  for(int i=0;i<40;++i){ int idx=base+i; s += (idx<N_NODES)? cnt[idx]:0; }
  ssum[t]=s; __syncthreads();
  if(t==0){ int run=0; for(int i=0;i<256;++i){ int v=ssum[i]; ssum[i]=run; run+=v; } }
  __syncthreads();
  int run=ssum[t];
  for(int i=0;i<40;++i){
    int idx=base+i;
    if(idx<N_NODES){ rowptr[idx]=run; pos[idx]=run; run+=cnt[idx]; }
  }
  if(t==255) rowptr[N_NODES]=run;
}

__global__ __launch_bounds__(256) void csr_scatter_k(const int* __restrict__ edst,
    int* __restrict__ pos, int* __restrict__ sorted){
  int e=blockIdx.x*256+threadIdx.x; if(e>=N_EDGES) return;
  int p=atomicAdd(&pos[edst[e]],1);
  sorted[p]=e;
}

// =====================================================================
// CG tables (device, double precision, exact replica of reference)
// =====================================================================
__device__ __forceinline__ double dfact(int n){
  const double F[11]={1.,1.,2.,6.,24.,120.,720.,5040.,40320.,362880.,3628800.};
  return F[n];
}

__device__ double cgc_d(int j1,int m1,int j2,int m2,int j3,int m3){
  if (m1+m2!=m3) return 0.0;
  double pre = sqrt((double)(2*j3+1)*dfact(j3+j1-j2)*dfact(j3-j1+j2)*dfact(j1+j2-j3)/dfact(j1+j2+j3+1));
  pre *= sqrt(dfact(j3+m3)*dfact(j3-m3)*dfact(j1-m1)*dfact(j1+m1)*dfact(j2-m2)*dfact(j2+m2));
  int k0 = max(0, max(j2-j3-m1, j1-j3+m2));
  int k1 = min(j1+j2-j3, min(j1-m1, j2+m2));
  double s=0.0;
  for(int k=k0;k<=k1;++k)
    s += ((k&1)?-1.0:1.0)/(dfact(k)*dfact(j1+j2-j3-k)*dfact(j1-m1-k)*dfact(j2+m2-k)*dfact(j3-j2+m1+k)*dfact(j3-j1-m2+k));
  return pre*s;
}

__device__ void c2r_d(int l,int a,int m,double&re,double&im){
  re=0.0; im=0.0;
  const double r2 = 0.7071067811865475244;
  int mu = a-l;
  if (mu==0){ if (m==l) re=1.0; return; }
  if (mu>0){
    if (m==l+mu) re = (mu&1)? -r2 : r2;
    else if (m==l-mu) re = r2;
  } else {
    int nu=-mu;
    if (m==l-nu) im = r2;
    else if (m==l+nu) im = (nu&1)? r2 : -r2;
  }
}

__global__ __launch_bounds__(128) void cg_init_k(float* cg){
  int b=blockIdx.x;
  int l1=b/9, l2=(b/3)%3, l3=b%3;
  if (l3 < iabs(l1-l2) || l3 > l1+l2) return;
  int n1=2*l1+1,n2=2*l2+1,n3=2*l3+1,n=n1*n2*n3;
  __shared__ double sRe[125], sIm[125];
  __shared__ int sPick;
  int t=threadIdx.x;
  if (t<n){
    int a=t/(n2*n3), bb=(t/n3)%n2, c=t%n3;
    double re=0.0, im=0.0;
    for(int m1=0;m1<n1;++m1){
      double q1r,q1i; c2r_d(l1,a,m1,q1r,q1i);
      if (q1r==0.0 && q1i==0.0) continue;
      for(int m2=0;m2<n2;++m2){
        double q2r,q2i; c2r_d(l2,bb,m2,q2r,q2i);
        if (q2r==0.0 && q2i==0.0) continue;
        int m3=(m1-l1)+(m2-l2)+l3;
        if (m3<0||m3>=n3) continue;
        double q3r,q3i; c2r_d(l3,c,m3,q3r,q3i); q3i=-q3i;
        double C = cgc_d(l1,m1-l1,l2,m2-l2,l3,m3-l3);
        if (C==0.0) continue;
        double ar = q1r*q2r - q1i*q2i;
        double ai = q1r*q2i + q1i*q2r;
        re += (ar*q3r - ai*q3i)*C;
        im += (ar*q3i + ai*q3r)*C;
      }
    }
    sRe[t]=re; sIm[t]=im;
  }
  __syncthreads();
  if (t==0){
    double s1=0.0,s2=0.0;
    for(int i=0;i<n;++i){ s1+=fabs(sRe[i]); s2+=fabs(sIm[i]); }
    sPick = (s1>=s2)?1:0;
  }
  __syncthreads();
  if (t<n) cg[b*125+t] = (float)(sPick? sRe[t] : sIm[t]);
}

// =====================================================================
// Stage A: x1 = tanh(f_in @ W(2x2) / sqrt(2))
// =====================================================================
__global__ __launch_bounds__(256) void nodeA_k(const float* __restrict__ fin,
                                               const float* __restrict__ w,
                                               float* __restrict__ x1){
  int n=blockIdx.x*256+threadIdx.x; if(n>=N_NODES) return;
  float f0=fin[2*n], f1=fin[2*n+1];
  const float r2=0.70710678f;
  x1[2*n]   = tanhf((f0*w[0]+f1*w[2])*r2);
  x1[2*n+1] = tanhf((f0*w[1]+f1*w[3])*r2);
}

// MLP [1,16,16,16] layers 0..2 of fc_apply (relu after each)
__device__ __forceinline__ void mlp16(float e, const float* w, float* h){
  float a[16];
  #pragma unroll
  for(int j=0;j<16;++j) a[j]=fmaxf(e*w[j],0.f);
  float b[16];
  #pragma unroll
  for(int j=0;j<16;++j){
    float s=0.f;
    #pragma unroll
    for(int i=0;i<16;++i) s+=a[i]*w[16+i*16+j];
    b[j]=fmaxf(s*0.25f,0.f);
  }
  #pragma unroll
  for(int j=0;j<16;++j){
    float s=0.f;
    #pragma unroll
    for(int i=0;i<16;++i) s+=b[i]*w[272+i*16+j];
    h[j]=fmaxf(s*0.25f,0.f);
  }
}

__global__ __launch_bounds__(256) void hmlp_k(const float* __restrict__ emb,
    const float* __restrict__ wfc, float* __restrict__ H, int E){
  __shared__ float sw[528];
  for(int t=threadIdx.x;t<528;t+=256) sw[t]=wfc[t];
  __syncthreads();
  int e=blockIdx.x*256+threadIdx.x; if(e>=E) return;
  float h[16]; mlp16(emb[e], sw, h);
  float4* H4=(float4*)(H+(size_t)e*16);
  #pragma unroll
  for(int q=0;q<4;++q) H4[q]=make_float4(h[4*q],h[4*q+1],h[4*q+2],h[4*q+3]);
}

__global__ __launch_bounds__(256) void hb_k(const float* __restrict__ emb,
    const float* __restrict__ wfc, const int* __restrict__ i0,
    const int* __restrict__ i1, const int* __restrict__ i2,
    float* __restrict__ HB){
  __shared__ float sw[528];
  for(int t=threadIdx.x;t<528;t+=256) sw[t]=wfc[t];
  __syncthreads();
  int t=blockIdx.x*256+threadIdx.x; if(t>=3*N_BONDS) return;
  const int* ind = (t<N_BONDS)? i0 : (t<2*N_BONDS? i1 : i2);
  int ie = ind[t%N_BONDS];
  float h[16]; mlp16(emb[ie], sw, h);
  float4* H4=(float4*)(HB+(size_t)t*16);
  #pragma unroll
  for(int q=0;q<4;++q) H4[q]=make_float4(h[4*q],h[4*q+1],h[4*q+2],h[4*q+3]);
}

// =====================================================================
// C[e_local x N] = 0.25 * A[arow(R0+e_local) x 16] * B[16 x N]
// arow = idx ? idx[g] : g.  Eloc rows starting at global row R0.
// =====================================================================
__global__ __launch_bounds__(256) void gemm16_k(const float* __restrict__ A,
    const float* __restrict__ B, float* __restrict__ C, int Eloc, int N,
    const int* __restrict__ idx, int R0){
  __shared__ float As[64][16];
  int tid=threadIdx.x;
  int et=blockIdx.x, ct=blockIdx.y;
  for(int t=tid;t<64*16;t+=256){
    int r=t/16, i=t%16;
    int e=et*64+r;
    int ea=-1;
    if (e<Eloc){ int g=R0+e; ea = idx? idx[g] : g; }
    As[r][i]=(ea>=0)? A[(size_t)ea*16+i] : 0.f;
  }
  __syncthreads();
  int col=ct*64+(tid&63);
  int eq=tid>>6;
  bool colok = col<N;
  float Breg[16];
  #pragma unroll
  for(int i=0;i<16;++i) Breg[i]= colok? B[(size_t)i*N+col]*0.25f : 0.f;
  #pragma unroll 4
  for(int es=0;es<16;++es){
    int e=et*64+eq*16+es;
    if (e>=Eloc) break;
    float acc=0.f;
    #pragma unroll
    for(int i=0;i<16;++i) acc+=As[eq*16+es][i]*Breg[i];
    if (colok) C[(size_t)e*N+col]=acc;
  }
}

// =====================================================================
// Edge conv 1 GATHER: one thread per node, CSR-ordered weights.
// =====================================================================
__global__ __launch_bounds__(256) void edge1g_k(const float* __restrict__ x1,
    const float* __restrict__ sh, const float* __restrict__ ww1,
    const int* __restrict__ esrc, const int* __restrict__ sorted,
    const int* __restrict__ rowptr, const float* __restrict__ nnb,
    float* __restrict__ xout){
  int n=blockIdx.x*256+threadIdx.x; if(n>=N_NODES) return;
  float inv = rsqrtf(nnb[0]);
  const float c = 0.70710678f*inv;
  float acc[72];
  #pragma unroll
  for(int t=0;t<72;++t) acc[t]=0.f;
  int r0=rowptr[n], r1=rowptr[n+1];
  for(int r=r0;r<r1;++r){
    int e=sorted[r];
    int src=esrc[e];
    float a0=x1[2*src], a1=x1[2*src+1];
    const float4* wr4=(const float4*)(ww1+(size_t)r*48);
    float wr[48];
    #pragma unroll
    for(int q=0;q<12;++q){ float4 v=wr4[q]; wr[4*q]=v.x; wr[4*q+1]=v.y; wr[4*q+2]=v.z; wr[4*q+3]=v.w; }
    float b[9];
    #pragma unroll
    for(int j=0;j<9;++j) b[j]=sh[(size_t)e*9+j];
    #pragma unroll
    for(int w8=0;w8<8;++w8){
      float s0=wr[w8]*a0+wr[8+w8]*a1;
      acc[w8]+=s0*b[0];
      float s1=wr[16+w8]*a0+wr[24+w8]*a1;
      #pragma unroll
      for(int j=0;j<3;++j) acc[8+w8*3+j]+=s1*b[1+j];
      float s2=wr[32+w8]*a0+wr[40+w8]*a1;
      #pragma unroll
      for(int j=0;j<5;++j) acc[32+w8*5+j]+=s2*b[4+j];
    }
  }
  float* o=xout+(size_t)n*72;
  #pragma unroll
  for(int t=0;t<72;++t) o[t]=acc[t]*c;
}

// =====================================================================
// Block-diagonal linear (8ch per slice), /sqrt(8), optional tanh
// =====================================================================
template<int L>
__device__ __forceinline__ void diag_block(float* Xs, const float* __restrict__ w, bool dotanh){
  constexpr int D=2*L+1;
  const float r8=0.35355339f;
  float in[8*D];
  #pragma unroll
  for(int t=0;t<8*D;++t) in[t]=Xs[t];
  #pragma unroll
  for(int v=0;v<8;++v){
    #pragma unroll
    for(int i=0;i<D;++i){
      float acc=0.f;
      #pragma unroll
      for(int u=0;u<8;++u) acc+=in[u*D+i]*w[u*8+v];
      acc*=r8;
      Xs[v*D+i]= dotanh? tanhf(acc):acc;
    }
  }
}

__global__ __launch_bounds__(256) void lin2_k(float* __restrict__ x, const float* __restrict__ w){
  int n=blockIdx.x*256+threadIdx.x; if(n>=N_NODES) return;
  float* X=x+(size_t)n*72;
  diag_block<0>(X,    w,     true);
  diag_block<1>(X+8,  w+64,  false);
  diag_block<2>(X+32, w+128, false);
}

__global__ __launch_bounds__(256) void lin3_k(float* __restrict__ x, const float* __restrict__ w){
  int n=blockIdx.x*256+threadIdx.x; if(n>=N_NODES) return;
  float* X=x+(size_t)n*144;
  diag_block<0>(X,     w,     true);
  diag_block<0>(X+8,   w+64,  true);
  diag_block<1>(X+16,  w+128, false);
  diag_block<1>(X+40,  w+192, false);
  diag_block<2>(X+64,  w+256, false);
  diag_block<2>(X+104, w+320, false);
}

// =====================================================================
// Edge conv 2 GATHER (windowed): one wave per node; node handled by the
// chunk whose window [R0,R1) contains rowptr[n]. Weights in CSR order,
// local row = r-R0 (slack rows cover boundary-straddling nodes).
// Per-lane acc: 0e@0, 1e@2..4, 1o@5..7, 2e@8..12, 2o@13..17
// =====================================================================
template<int L1,int L2,int LO,int AO,int BO,int WB,int SLOT>
__device__ __forceinline__ void e2g_path(const float* __restrict__ A,
    const float* __restrict__ b, const float* __restrict__ cg,
    const float* __restrict__ wrow, int u, int lane, float* acc){
  constexpr int D1=2*L1+1, D2=2*L2+1, DN=2*LO+1;
  const float* C = cg + ((L1*3+L2)*3+LO)*125;
  float P[DN];
  #pragma unroll
  for(int k=0;k<DN;++k) P[k]=0.f;
  #pragma unroll
  for(int i=0;i<D1;++i){
    float av=A[AO+u*D1+i];
    #pragma unroll
    for(int j=0;j<D2;++j){
      float ab=av*b[BO+j];
      #pragma unroll
      for(int k=0;k<DN;++k){
        float cv=C[(i*D2+j)*DN+k];
        if(cv!=0.f) P[k]+=ab*cv;
      }
    }
  }
  float wv = wrow[WB + lane];
  #pragma unroll
  for(int k=0;k<DN;++k) acc[SLOT+k]+=wv*P[k];
}

__global__ __launch_bounds__(256) void edge2gw_k(const float* __restrict__ xn,
    const float* __restrict__ sh, const float* __restrict__ wbuf,
    const int* __restrict__ esrc, const int* __restrict__ sorted,
    const int* __restrict__ rowptr, const float* __restrict__ nnb,
    const float* __restrict__ cg, float* __restrict__ xout,
    int R0, int R1){
  int wid=threadIdx.x>>6, lane=threadIdx.x&63;
  int n=blockIdx.x*4+wid; if(n>=N_NODES) return;
  int r0=rowptr[n], r1=rowptr[n+1];
  if (r0<R0 || r0>=R1) return;
  int u=lane>>3, w=lane&7;
  float inv = rsqrtf(nnb[0]);
  float acc[18];
  #pragma unroll
  for(int t=0;t<18;++t) acc[t]=0.f;
  for(int r=r0;r<r1;++r){
    int e=sorted[r];
    const float* A = xn + (size_t)esrc[e]*72;
    float b[9];
    #pragma unroll
    for(int j=0;j<9;++j) b[j]=sh[(size_t)e*9+j];
    const float* wrow = wbuf + (size_t)(r-R0)*960;
    e2g_path<0,0,0, 0,0,   0, 0>(A,b,cg,wrow,u,lane,acc);
    e2g_path<1,1,0, 8,1, 256, 0>(A,b,cg,wrow,u,lane,acc);
    e2g_path<2,2,0,32,4, 768, 0>(A,b,cg,wrow,u,lane,acc);
    e2g_path<1,1,1, 8,1, 320, 2>(A,b,cg,wrow,u,lane,acc);
    e2g_path<2,2,1,32,4, 832, 2>(A,b,cg,wrow,u,lane,acc);
    e2g_path<0,1,1, 0,1,  64, 5>(A,b,cg,wrow,u,lane,acc);
    e2g_path<1,0,1, 8,0, 192, 5>(A,b,cg,wrow,u,lane,acc);
    e2g_path<1,2,1, 8,4, 448, 5>(A,b,cg,wrow,u,lane,acc);
    e2g_path<2,1,1,32,1, 640, 5>(A,b,cg,wrow,u,lane,acc);
    e2g_path<0,2,2, 0,4, 128, 8>(A,b,cg,wrow,u,lane,acc);
    e2g_path<1,1,2, 8,1, 384, 8>(A,b,cg,wrow,u,lane,acc);
    e2g_path<2,0,2,32,0, 576, 8>(A,b,cg,wrow,u,lane,acc);
    e2g_path<2,2,2,32,4, 896, 8>(A,b,cg,wrow,u,lane,acc);
    e2g_path<1,2,2, 8,4, 512,13>(A,b,cg,wrow,u,lane,acc);
    e2g_path<2,1,2,32,1, 704,13>(A,b,cg,wrow,u,lane,acc);
  }
  #pragma unroll
  for(int t=0;t<18;++t){
    acc[t]+=__shfl_xor(acc[t],8,64);
    acc[t]+=__shfl_xor(acc[t],16,64);
    acc[t]+=__shfl_xor(acc[t],32,64);
  }
  if (lane<8){
    float* o = xout + (size_t)n*144;
    float f0 =rsqrtf(24.f)*inv;
    float f1e=rsqrtf(16.f)*inv;
    float f1o=rsqrtf(32.f)*inv;
    float f2e=rsqrtf(32.f)*inv;
    float f2o=rsqrtf(16.f)*inv;
    o[0+w]=acc[0]*f0;
    o[8+w]=0.f;
    #pragma unroll
    for(int k=0;k<3;++k) o[16+w*3+k]=acc[2+k]*f1e;
    #pragma unroll
    for(int k=0;k<3;++k) o[40+w*3+k]=acc[5+k]*f1o;
    #pragma unroll
    for(int k=0;k<5;++k) o[64+w*5+k]=acc[8+k]*f2e;
    #pragma unroll
    for(int k=0;k<5;++k) o[104+w*5+k]=acc[13+k]*f2o;
  }
}

// =====================================================================
// Irrep linear (fan=8 per slice); zero-fills unmatched output slices.
// =====================================================================
struct IrS{ short off,m,l,p; };
__device__ const IrS SL_MID2[6]={{0,8,0,1},{8,8,0,-1},{16,8,1,1},{40,8,1,-1},{64,8,2,1},{104,8,2,-1}};
__device__ const IrS SL_HH[6]={{0,4,0,1},{4,2,1,-1},{10,2,1,-1},{16,1,0,1},{17,1,1,1},{20,1,2,1}};
__device__ const IrS SL_CC[34]={{0,9,0,1},{9,6,1,-1},{27,3,2,1},{42,6,1,-1},
 {60,1,0,1},{61,1,1,1},{64,1,2,1},{69,1,0,1},{70,1,1,1},{73,1,2,1},
 {78,1,0,1},{79,1,1,1},{82,1,2,1},{87,1,0,1},{88,1,1,1},{91,1,2,1},
 {96,1,1,-1},{99,1,2,-1},{104,1,3,-1},{111,1,1,-1},{114,1,2,-1},{119,1,3,-1},
 {126,3,2,1},{141,1,1,-1},{144,1,2,-1},{149,1,3,-1},{156,1,1,-1},{159,1,2,-1},{164,1,3,-1},
 {171,1,0,1},{172,1,1,1},{175,1,2,1},{180,1,3,1},{187,1,4,1}};
__device__ const IrS SL_CH[13]={{0,6,0,1},{6,3,1,-1},{15,4,1,-1},{27,1,0,1},{28,1,1,1},{31,1,2,1},
 {36,1,0,1},{37,1,1,1},{40,1,2,1},{45,2,2,1},{55,1,1,-1},{58,1,2,-1},{63,1,3,-1}};

__device__ void lin_out(const float* __restrict__ x, bool act16, const float* __restrict__ w,
                        const IrS* so, int no, int dim,
                        void* out, size_t base, bool f32o, float scale){
  float tx[16];
  if (act16){
    #pragma unroll
    for(int i=0;i<16;++i) tx[i]=tanhf(x[i]);
  }
  for(int i=0;i<dim;++i) stout(out, base+i, 0.f, f32o);
  int woff=0;
  for(int a=0;a<6;++a){
    int la=SL_MID2[a].l, pa=SL_MID2[a].p, oa=SL_MID2[a].off;
    int d=2*la+1;
    for(int bI=0;bI<no;++bI){
      if (so[bI].l!=la || so[bI].p!=pa) continue;
      int mo=so[bI].m;
      float f = 0.35355339f*scale;
      for(int v=0;v<mo;++v){
        for(int i=0;i<d;++i){
          float acc=0.f;
          for(int u=0;u<8;++u){
            int idx=oa+u*d+i;
            float xv=(act16 && idx<16)? tx[idx] : x[idx];
            acc+=xv*w[woff+u*mo+v];
          }
          stout(out, base+so[bI].off+v*d+i, acc*f, f32o);
        }
      }
      woff+=8*mo;
    }
  }
}

// =====================================================================
// Node outputs: nH, nC, screen
// =====================================================================
__global__ __launch_bounds__(256) void node_out_k(const float* __restrict__ x,
    const float* __restrict__ wC, const float* __restrict__ wH,
    const float* __restrict__ ws1, const float* __restrict__ ws2,
    void* out, const int* __restrict__ flag){
  int n=blockIdx.x*256+threadIdx.x; if(n>=N_NODES) return;
  bool f32o = (*flag)!=0;
  const float* X = x + (size_t)n*144;
  lin_out(X,false,wH,SL_HH,6,25,   out, (size_t)n*25, f32o, 0.2f);
  lin_out(X,false,wC,SL_CC,34,196, out, 250000 + (size_t)n*196, f32o, 0.2f);
  const float r8=0.35355339f, r32=0.17677670f;
  float t0[32];
  for(int v=0;v<32;++v){
    float acc=0.f;
    #pragma unroll
    for(int u=0;u<8;++u) acc+=X[u]*ws1[u*32+v];
    t0[v]=tanhf(acc*r8);
  }
  float t2[5];
  #pragma unroll
  for(int i=0;i<5;++i){
    float acc=0.f;
    #pragma unroll
    for(int u=0;u<8;++u) acc+=X[64+u*5+i]*ws1[256+u];
    t2[i]=acc*r8;
  }
  size_t sb = 2501000 + (size_t)n*6;
  float acc=0.f;
  for(int v=0;v<32;++v) acc+=t0[v]*ws2[v];
  stout(out, sb, acc*r32, f32o);
  float w2e=ws2[32];
  #pragma unroll
  for(int i=0;i<5;++i) stout(out, sb+1+i, t2[i]*w2e, f32o);
}

// =====================================================================
// Bond TP: one wave per bond, precomputed weights (coalesced reads)
// =====================================================================
template<int L1,int L2,int LO>
__device__ __forceinline__ void bond_pathb(const float* sa,int ao,const float* sb,int bo,
    const float* __restrict__ cg, const float* __restrict__ wrow, int wbase, float invfan,
    float* sP, float* sF, int oo, int lane){
  constexpr int D1=2*L1+1, D2=2*L2+1, DN=2*LO+1;
  const float* C = cg + ((L1*3+L2)*3+LO)*125;
  int u=lane>>3, v=lane&7;
  float P[DN];
  #pragma unroll
  for(int k=0;k<DN;++k) P[k]=0.f;
  #pragma unroll
  for(int i=0;i<D1;++i){
    float avv=sa[ao+u*D1+i];
    #pragma unroll
    for(int j=0;j<D2;++j){
      float ab=avv*sb[bo+v*D2+j];
      #pragma unroll
      for(int k=0;k<DN;++k){
        float cv=C[(i*D2+j)*DN+k];
        if(cv!=0.f) P[k]+=ab*cv;
      }
    }
  }
  #pragma unroll
  for(int k=0;k<DN;++k) sP[lane*5+k]=P[k];
  __syncthreads();
  int v2=lane>>3, w=lane&7;
  float acc[DN];
  #pragma unroll
  for(int k=0;k<DN;++k) acc[k]=0.f;
  #pragma unroll
  for(int u2=0;u2<8;++u2){
    float ww = wrow[wbase + u2*64 + lane];
    #pragma unroll
    for(int k=0;k<DN;++k) acc[k]+=ww*sP[(u2*8+v2)*5+k];
  }
  #pragma unroll
  for(int k=0;k<DN;++k){
    acc[k]+=__shfl_xor(acc[k],8,64);
    acc[k]+=__shfl_xor(acc[k],16,64);
    acc[k]+=__shfl_xor(acc[k],32,64);
  }
  if (v2==0){
    #pragma unroll
    for(int k=0;k<DN;++k) sF[oo+w*DN+k]+=acc[k]*invfan;
  }
  __syncthreads();
}

__device__ __forceinline__ void bond_body(const float* xn, const float* wrow,
    int src, int dst, const float* cg, float* Fout, int wid, int lane,
    float sA[4][144], float sB[4][144], float sF[4][144], float sP[4][320], bool act){
  for(int t=lane;t<144;t+=64){
    sA[wid][t]=xn[(size_t)src*144+t];
    sB[wid][t]=xn[(size_t)dst*144+t];
    sF[wid][t]=0.f;
  }
  __syncthreads();
  const int SL_L[6]={0,0,1,1,2,2};
  const int SL_P[6]={1,-1,1,-1,1,-1};
  const int SL_O[6]={0,8,16,40,64,104};
  const float fi0=rsqrtf(384.f), fi1=rsqrtf(768.f);
  int wbase=0;
  for(int s1=0;s1<6;++s1){
    for(int s2=0;s2<6;++s2){
      for(int so=0;so<6;++so){
        int l1=SL_L[s1], l2=SL_L[s2], lo=SL_L[so];
        if (SL_P[so]!=SL_P[s1]*SL_P[s2]) continue;
        if (lo<iabs(l1-l2) || lo>l1+l2) continue;
        int code=l1*9+l2*3+lo;
        float* a=sA[wid]; float* bb=sB[wid]; float* P=sP[wid]; float* F=sF[wid];
        int ao=SL_O[s1], bo=SL_O[s2], oo=SL_O[so];
        float fv = (lo==0)? fi0 : fi1;
        switch(code){
          case 0:  bond_pathb<0,0,0>(a,ao,bb,bo,cg,wrow,wbase,fv,P,F,oo,lane); break;
          case 4:  bond_pathb<0,1,1>(a,ao,bb,bo,cg,wrow,wbase,fv,P,F,oo,lane); break;
          case 8:  bond_pathb<0,2,2>(a,ao,bb,bo,cg,wrow,wbase,fv,P,F,oo,lane); break;
          case 10: bond_pathb<1,0,1>(a,ao,bb,bo,cg,wrow,wbase,fv,P,F,oo,lane); break;
          case 12: bond_pathb<1,1,0>(a,ao,bb,bo,cg,wrow,wbase,fv,P,F,oo,lane); break;
          case 13: bond_pathb<1,1,1>(a,ao,bb,bo,cg,wrow,wbase,fv,P,F,oo,lane); break;
          case 14: bond_pathb<1,1,2>(a,ao,bb,bo,cg,wrow,wbase,fv,P,F,oo,lane); break;
          case 16: bond_pathb<1,2,1>(a,ao,bb,bo,cg,wrow,wbase,fv,P,F,oo,lane); break;
          case 17: bond_pathb<1,2,2>(a,ao,bb,bo,cg,wrow,wbase,fv,P,F,oo,lane); break;
          case 20: bond_pathb<2,0,2>(a,ao,bb,bo,cg,wrow,wbase,fv,P,F,oo,lane); break;
          case 22: bond_pathb<2,1,1>(a,ao,bb,bo,cg,wrow,wbase,fv,P,F,oo,lane); break;
          case 23: bond_pathb<2,1,2>(a,ao,bb,bo,cg,wrow,wbase,fv,P,F,oo,lane); break;
          case 24: bond_pathb<2,2,0>(a,ao,bb,bo,cg,wrow,wbase,fv,P,F,oo,lane); break;
          case 25: bond_pathb<2,2,1>(a,ao,bb,bo,cg,wrow,wbase,fv,P,F,oo,lane); break;
          case 26: bond_pathb<2,2,2>(a,ao,bb,bo,cg,wrow,wbase,fv,P,F,oo,lane); break;
        }
        wbase+=512;
      }
    }
  }
  __syncthreads();
  if (act){
    for(int t=lane;t<144;t+=64) Fout[t]=sF[wid][t];
  }
  __syncthreads();
}

// merged consumer over all 3 bond sets, chunk window [gb0, gb1)
__global__ __launch_bounds__(256) void bond_tpm_k(const float* __restrict__ xn,
    const float* __restrict__ wwb,
    const int* __restrict__ esrc, const int* __restrict__ edst,
    const int* __restrict__ i0, const int* __restrict__ i1, const int* __restrict__ i2,
    const float* __restrict__ cg,
    float* __restrict__ F0, float* __restrict__ F1, float* __restrict__ F2,
    int gb0, int gb1){
  __shared__ float sA[4][144], sB[4][144], sF[4][144], sP[4][320];
  int wid=threadIdx.x>>6, lane=threadIdx.x&63;
  int gb=gb0+blockIdx.x*4+wid;
  bool act = gb<gb1;
  int gbe = act? gb : gb0;
  int s=gbe/N_BONDS, bi=gbe%N_BONDS;
  const int* ind = (s==0)? i0 : (s==1)? i1 : i2;
  float* F = (s==0)? F0 : (s==1)? F1 : F2;
  int ie=ind[bi];
  bond_body(xn, wwb+(size_t)(gbe-gb0)*30720, esrc[ie], edst[ie], cg,
            F+(size_t)bi*144, wid, lane, sA,sB,sF,sP, act);
}

// =====================================================================
// Bond outputs
// =====================================================================
__global__ __launch_bounds__(256) void bond_out_k(const float* __restrict__ F,
    const float* __restrict__ wlin, int tbl, void* out, size_t baseE,
    const float* __restrict__ wg1, const float* __restrict__ wg2,
    size_t baseG, const int* __restrict__ flag){
  int n=blockIdx.x*256+threadIdx.x; if(n>=N_BONDS) return;
  bool f32o = (*flag)!=0;
  const float* X=F+(size_t)n*144;
  const IrS* so; int no; int dim;
  if(tbl==0){so=SL_HH;no=6;dim=25;}
  else if(tbl==1){so=SL_CC;no=34;dim=196;}
  else {so=SL_CH;no=13;dim=70;}
  lin_out(X,true,wlin,so,no,dim,out,baseE+(size_t)n*dim,f32o,0.2f);
  const float r8=0.35355339f, r32=0.17677670f;
  float g[32];
  for(int v=0;v<32;++v){
    float acc=0.f;
    #pragma unroll
    for(int u=0;u<8;++u) acc+=X[u]*wg1[u*32+v];
    g[v]=tanhf(acc*r8);
  }
  #pragma unroll
  for(int c=0;c<3;++c){
    float acc=0.f;
    for(int v=0;v<32;++v) acc+=g[v]*wg2[v*3+c];
    stout(out, baseG+(size_t)n*3+c, acc*r32, f32o);
  }
}

// =====================================================================
extern "C" void kernel_launch(void* const* d_in, const int* in_sizes, int n_in,
                              void* d_out, int out_size, void* d_ws, size_t ws_size,
                              hipStream_t stream){
  const int* esrc=(const int*)d_in[19];
  const int* edst=(const int*)d_in[20];
  const int* iHH =(const int*)d_in[21];
  const int* iCC =(const int*)d_in[22];
  const int* iCH =(const int*)d_in[23];
  float* ws=(float*)d_ws;
  int* flag=(int*)d_ws;

  size_t off=16;
  auto alloc=[&](size_t n){ size_t o=off; off+=(n+15)&~(size_t)15; return o; };
  size_t o_cg = alloc(27*125);
  size_t o_st[19];
  for(int i=0;i<19;++i) o_st[i]=alloc((size_t)in_sizes[i]);
  size_t o_x1  = alloc(20000);
  size_t o_xM1 = alloc(720000);
  size_t o_xM2 = alloc(1440000);
  size_t o_F0  = alloc(144000);
  size_t o_F1  = alloc(144000);
  size_t o_F2  = alloc(144000);
  size_t o_h1  = alloc((size_t)N_EDGES*16);
  size_t o_h2  = alloc((size_t)N_EDGES*16);
  size_t o_hb  = alloc((size_t)3*N_BONDS*16);
  size_t o_ww1 = alloc((size_t)N_EDGES*48);
  size_t o_cnt = alloc(10016);
  size_t o_rp  = alloc(10016);
  size_t o_pos = alloc(10016);
  size_t o_srt = alloc(N_EDGES);
  size_t o_big = off;

  size_t avail = ws_size/4;
  size_t remain = (avail > o_big)? (avail - o_big) : 0;
  // edge2 window size (rows) with 4096-row slack for boundary nodes
  const int SLACK = 4096;
  long RCm = (long)(remain/960) - SLACK;
  if (RCm < 1024) RCm = 1024;               // last-resort clamp
  if (RCm > N_EDGES) RCm = N_EDGES;
  // bond chunk (rows of 30720)
  int bchunk = (int)((remain)/30720);
  if (bchunk < 1) bchunk = 1;
  if (bchunk > 3*N_BONDS) bchunk = 3*N_BONDS;

  float* cg  = ws+o_cg;
  float* x1  = ws+o_x1;
  float* xM1 = ws+o_xM1;
  float* xM2 = ws+o_xM2;
  float* F0  = ws+o_F0;
  float* F1  = ws+o_F1;
  float* F2  = ws+o_F2;
  float* h1  = ws+o_h1;
  float* h2  = ws+o_h2;
  float* hb  = ws+o_hb;
  float* ww1 = ws+o_ww1;
  int* cnt   = (int*)(ws+o_cnt);
  int* rowptr= (int*)(ws+o_rp);
  int* pos   = (int*)(ws+o_pos);
  int* sorted= (int*)(ws+o_srt);
  float* wbuf= ws+o_big;

  CvtArgs ca;
  for(int i=0;i<19;++i){ ca.src[i]=d_in[i]; ca.dst[i]=ws+o_st[i]; ca.n[i]=in_sizes[i]; }
  const float* f_in   = ws+o_st[0];
  const float* sh     = ws+o_st[1];
  const float* emb    = ws+o_st[2];
  const float* nnb    = ws+o_st[3];
  const float* w_lin1 = ws+o_st[4];
  const float* w_lin2 = ws+o_st[5];
  const float* w_lin3 = ws+o_st[6];
  const float* w_linCC= ws+o_st[7];
  const float* w_linHH= ws+o_st[8];
  const float* w_linCH= ws+o_st[9];
  const float* w_linC = ws+o_st[10];
  const float* w_linH = ws+o_st[11];
  const float* w_s1   = ws+o_st[12];
  const float* w_s2   = ws+o_st[13];
  const float* w_g1   = ws+o_st[14];
  const float* w_g2   = ws+o_st[15];
  const float* w_fc1  = ws+o_st[16];
  const float* w_fc2  = ws+o_st[17];
  const float* w_fcb  = ws+o_st[18];

  detect_k<<<1,1,0,stream>>>((const unsigned short*)d_in[3], flag);
  convert_k<<<512,256,0,stream>>>(ca, flag);
  cg_init_k<<<27,128,0,stream>>>(cg);
  // CSR by destination
  hipMemsetAsync(cnt, 0, 10000*sizeof(int), stream);
  csr_count_k<<<391,256,0,stream>>>(edst, cnt);
  csr_scan_k<<<1,256,0,stream>>>(cnt, rowptr, pos);
  csr_scatter_k<<<391,256,0,stream>>>(edst, pos, sorted);

  nodeA_k<<<40,256,0,stream>>>(f_in,w_lin1,x1);
  hmlp_k<<<391,256,0,stream>>>(emb, w_fc1, h1, N_EDGES);
  hmlp_k<<<391,256,0,stream>>>(emb, w_fc2, h2, N_EDGES);
  hb_k<<<12,256,0,stream>>>(emb, w_fcb, iHH, iCC, iCH, hb);

  // edge conv 1 (gather, CSR-ordered weights)
  gemm16_k<<<dim3(1563,1),256,0,stream>>>(h1, w_fc1+528, ww1, N_EDGES, 48, sorted, 0);
  edge1g_k<<<40,256,0,stream>>>(x1,sh,ww1,esrc,sorted,rowptr,nnb,xM1);
  lin2_k<<<40,256,0,stream>>>(xM1,w_lin2);

  // edge conv 2: windowed CSR-ordered weight GEMM + gather consumer
  for(long R0=0; R0<N_EDGES; R0+=RCm){
    int Eloc = (int)min((long)(RCm+SLACK), (long)N_EDGES-R0);
    gemm16_k<<<dim3((Eloc+63)/64,15),256,0,stream>>>(h2, w_fc2+528, wbuf, Eloc, 960, sorted, (int)R0);
    edge2gw_k<<<2500,256,0,stream>>>(xM1,sh,wbuf,esrc,sorted,rowptr,nnb,cg,xM2,(int)R0,(int)(R0+RCm));
  }
  lin3_k<<<40,256,0,stream>>>(xM2,w_lin3);
  node_out_k<<<40,256,0,stream>>>(xM2,w_linC,w_linH,w_s1,w_s2,d_out,flag);

  // bonds: chunked merged GEMM + merged consumer
  for(int gb0=0; gb0<3*N_BONDS; gb0+=bchunk){
    int Bc = min(bchunk, 3*N_BONDS-gb0);
    gemm16_k<<<dim3((Bc+63)/64,480),256,0,stream>>>(hb, w_fcb+528, wbuf, Bc, 30720, (const int*)nullptr, gb0);
    bond_tpm_k<<<(Bc+3)/4,256,0,stream>>>(xM2,wbuf,esrc,edst,iHH,iCC,iCH,cg,F0,F1,F2,gb0,gb0+Bc);
  }
  // outputs: 0:nH@0 1:nC@250000 2:eHH@2210000 3:eCH@2235000 4:eCC@2305000
  //          5:screen@2501000 6:gapCC@2561000 7:gapHH@2564000 8:gapCH@2567000
  bond_out_k<<<4,256,0,stream>>>(F0,w_linHH,0,d_out,2210000,w_g1,w_g2,2564000,flag);
  bond_out_k<<<4,256,0,stream>>>(F1,w_linCC,1,d_out,2305000,w_g1,w_g2,2561000,flag);
  bond_out_k<<<4,256,0,stream>>>(F2,w_linCH,2,d_out,2235000,w_g1,w_g2,2567000,flag);
}